// Round 1
// baseline (1077.385 us; speedup 1.0000x reference)
//
#include <hip/hip_runtime.h>
#include <math.h>

#define BB 16
#define H2N 512
#define EMBN 128
#define KKN 4
#define NRN 5
#define LRN 100
#define LQN 60
#define NQN 5
#define VOCABN 50000
#define EXTRAN 100
#define LTOT 460
#define EPSF 1e-12f

__device__ __forceinline__ float sigm(float x){ return 1.0f/(1.0f+expf(-x)); }

// ---------------------------------------------------------------- K1: LSTM
__global__ __launch_bounds__(256) void k_lstm(
    const float* __restrict__ y_t, const float* __restrict__ h0, const float* __restrict__ c0,
    const float* __restrict__ c_t_0, const float* __restrict__ xc_w, const float* __restrict__ xc_b,
    const float* __restrict__ w_ih, const float* __restrict__ w_hh,
    const float* __restrict__ b_ih, const float* __restrict__ b_hh,
    float* __restrict__ sthat, float* __restrict__ out_h1, float* __restrict__ out_c1)
{
  __shared__ float cat[640], xl[128], h0s[256];
  int b = blockIdx.x, t = threadIdx.x;
  for (int d=t; d<640; d+=256) cat[d] = (d<128)? y_t[b*128+d] : c_t_0[b*512+(d-128)];
  h0s[t] = h0[b*256+t];
  __syncthreads();
  if (t<128) {
    float acc = xc_b[t];
    const float* row = xc_w + t*640;
    #pragma unroll 4
    for (int d=0; d<640; ++d) acc += cat[d]*row[d];
    xl[t] = acc;
  }
  __syncthreads();
  int j = t;
  float g4[4];
  #pragma unroll
  for (int gi=0; gi<4; ++gi) {
    int r = gi*256 + j;
    float acc = b_ih[r] + b_hh[r];
    const float* wi = w_ih + r*128;
    #pragma unroll 4
    for (int d=0; d<128; ++d) acc += xl[d]*wi[d];
    const float* wh = w_hh + r*256;
    #pragma unroll 4
    for (int d=0; d<256; ++d) acc += h0s[d]*wh[d];
    g4[gi] = acc;
  }
  // gate order i,f,g,o
  float c1v = sigm(g4[1])*c0[b*256+j] + sigm(g4[0])*tanhf(g4[2]);
  float h1v = sigm(g4[3])*tanhf(c1v);
  sthat[b*512+j] = h1v; sthat[b*512+256+j] = c1v;
  out_h1[b*256+j] = h1v; out_c1[b*256+j] = c1v;
}

// ------------------------------------------- K2: dynamic-select weights + WsS
__global__ __launch_bounds__(128) void k_ds(
    const float* __restrict__ sthat, const float* __restrict__ o_m,
    const float* __restrict__ q_a, const float* __restrict__ r_a, const float* __restrict__ r_o,
    const float* __restrict__ dsq_w, const float* __restrict__ dsa_w, const float* __restrict__ dso_w,
    const float* __restrict__ Ws_w,
    float* __restrict__ wq_o, float* __restrict__ qat_o, float* __restrict__ cw_o,
    float* __restrict__ WsS_o)
{
  __shared__ float s[512], om[640], qat[128], tmpv[128], wr[20], wa_l[20], wsum[4], wq_l[8];
  int b = blockIdx.x, t = threadIdx.x;
  for (int i=t;i<512;i+=128) s[i]=sthat[b*512+i];
  for (int i=t;i<640;i+=128) om[i]=o_m[b*640+i];
  __syncthreads();
  { float acc=0; for(int d=0;d<512;++d) acc += s[d]*dsq_w[d*128+t]; tmpv[t]=acc; }
  __syncthreads();
  if (t<5){ float acc=0; const float* qa = q_a + (b*5+t)*128;
            for(int e2=0;e2<128;++e2) acc+=tmpv[e2]*qa[e2]; wr[t]=tanhf(acc);}
  __syncthreads();
  if (t==0){ float sm=EPSF; for(int n=0;n<5;++n) sm+=wr[n]; wsum[0]=sm; }
  __syncthreads();
  if (t<5){ float v = wr[t]/wsum[0]; wq_l[t]=v; wq_o[b*5+t]=v; }
  __syncthreads();
  { float acc=0; for(int n=0;n<5;++n) acc += wq_l[n]*q_a[(b*5+n)*128+t];
    qat[t]=acc; qat_o[b*128+t]=acc; }
  __syncthreads();
  { float acc=0;
    for(int d=0;d<512;++d) acc += s[d]*dsa_w[d*128+t];
    for(int d=0;d<128;++d) acc += qat[d]*dsa_w[(512+d)*128+t];
    tmpv[t]=acc; }
  __syncthreads();
  if (t<20){ int k=t/5; float acc=0; const float* ra = r_a + ((b*4+k)*5 + (t%5))*128;
             for(int e2=0;e2<128;++e2) acc+=tmpv[e2]*ra[e2]; wr[t]=tanhf(acc);}
  __syncthreads();
  if (t<4){ float sm=EPSF; for(int n=0;n<5;++n) sm+=wr[t*5+n]; wsum[t]=sm; }
  __syncthreads();
  if (t<20){ wa_l[t] = wr[t]/wsum[t/5]; }
  __syncthreads();
  { float acc=0;
    for(int d=0;d<512;++d) acc += s[d]*dso_w[d*128+t];
    for(int d=0;d<640;++d) acc += om[d]*dso_w[(512+d)*128+t];
    tmpv[t]=acc; }
  __syncthreads();
  if (t<20){ int k=t/5; float acc=0; const float* ro = r_o + ((b*4+k)*5 + (t%5))*128;
             for(int e2=0;e2<128;++e2) acc+=tmpv[e2]*ro[e2]; wr[t]=tanhf(acc);}
  __syncthreads();
  if (t<4){ float sm=EPSF; for(int n=0;n<5;++n) sm+=wr[t*5+n]; wsum[t]=sm; }
  __syncthreads();
  if (t<20){ cw_o[b*20 + t] = wa_l[t] + wr[t]/wsum[t/5]; }
  // WsS[b,h] = sum_d sthat[b,d]*Ws_w[h,d]
  for (int jj=0; jj<4; ++jj){
    int h = t + jj*128;
    float acc=0; const float* row = Ws_w + h*512;
    #pragma unroll 4
    for(int d=0;d<512;++d) acc += s[d]*row[d];
    WsS_o[b*512+h]=acc;
  }
}

// -------------------------------------- K3: q_t / r_t weighted sums (flat f4)
#define NQT4 (BB*LQN*128)
__global__ __launch_bounds__(256) void k_wsum(
    const float* __restrict__ h_q, const float* __restrict__ h_r,
    const float* __restrict__ wq, const float* __restrict__ cw,
    float* __restrict__ q_t, float* __restrict__ r_t)
{
  __shared__ float cf[5];
  long idx = (long)blockIdx.x*256 + threadIdx.x;
  if (blockIdx.x < 480) {
    int b = (int)(idx / (LQN*128));
    if (threadIdx.x < 5) cf[threadIdx.x] = wq[b*5+threadIdx.x];
    __syncthreads();
    int rem = (int)(idx % (LQN*128));
    int l = rem/128, h4 = rem&127;
    const float4* src = (const float4*)h_q;
    float4 acc = {0,0,0,0};
    #pragma unroll
    for (int n=0;n<5;++n){
      float4 v = src[(((long)(b*5+n)*LQN + l)<<7) + h4];
      float w = cf[n];
      acc.x += w*v.x; acc.y += w*v.y; acc.z += w*v.z; acc.w += w*v.w;
    }
    ((float4*)q_t)[((long)(b*LQN+l)<<7) + h4] = acc;
  } else {
    long j = idx - NQT4;
    int bk = (int)(j / (LRN*128));
    if (threadIdx.x < 5) cf[threadIdx.x] = cw[bk*5+threadIdx.x];
    __syncthreads();
    int rem = (int)(j % (LRN*128));
    int l = rem/128, h4 = rem&127;
    const float4* src = (const float4*)h_r;
    float4 acc = {0,0,0,0};
    #pragma unroll
    for (int n=0;n<5;++n){
      float4 v = src[(((long)(bk*5+n)*LRN + l)<<7) + h4];
      float w = cf[n];
      acc.x += w*v.x; acc.y += w*v.y; acc.z += w*v.z; acc.w += w*v.w;
    }
    ((float4*)r_t)[((long)(bk*LRN+l)<<7) + h4] = acc;
  }
}

// ---------------------------------------------------- K4: qU = q_t @ U_w^T
__global__ __launch_bounds__(256) void k_qU(
    const float* __restrict__ q_t, const float* __restrict__ U_w, float* __restrict__ qU)
{
  __shared__ float qt[4*512];
  int bid = blockIdx.x; int b = bid/15, tile = bid%15, q0 = tile*4, t = threadIdx.x;
  for (int i=t;i<2048;i+=256) qt[i] = q_t[(long)(b*60+q0)*512 + i];
  __syncthreads();
  float acc[4][2] = {};
  const float4* w1 = (const float4*)(U_w + (long)t*512);
  const float4* w2 = (const float4*)(U_w + (long)(t+256)*512);
  const float4* qv = (const float4*)qt;
  for (int hp=0; hp<128; ++hp){
    float4 a = w1[hp], c = w2[hp];
    #pragma unroll
    for (int qi=0; qi<4; ++qi){
      float4 p = qv[qi*128+hp];
      acc[qi][0] += p.x*a.x+p.y*a.y+p.z*a.z+p.w*a.w;
      acc[qi][1] += p.x*c.x+p.y*c.y+p.z*c.z+p.w*c.w;
    }
  }
  #pragma unroll
  for (int qi=0;qi<4;++qi){
    qU[(long)(b*60+q0+qi)*512 + t]       = acc[qi][0];
    qU[(long)(b*60+q0+qi)*512 + 256 + t] = acc[qi][1];
  }
}

// ------------------------- K5: U = tanh(qU·r_t^T): maxes + alpha softmaxes
__global__ __launch_bounds__(256) void k_umax(
    const float* __restrict__ qU, const float* __restrict__ r_t,
    float* __restrict__ aq, float* __restrict__ ar)
{
  // stride-33 padding: stride-32 rows would put every column on one bank
  __shared__ float qt[60*33];
  __shared__ float rt[102*33];
  __shared__ float mqb[60*17];
  __shared__ float mrb[100*15];
  __shared__ float uq[60], ur[100], scal[4];
  int bid = blockIdx.x; int b = bid>>2, k = bid&3, t = threadIdx.x;
  bool act = t < 255;
  int tq = t/17, tr = t%17;
  int q0 = tq*4, r0 = tr*6;
  int nv = (r0+6<=100)? 6 : (100-r0);
  float acc[4][6] = {};
  const float* qbase = qU + (long)b*60*512;
  const float* rbase = r_t + (long)(b*4+k)*100*512;
  for (int c=0;c<16;++c){
    for (int i=t;i<60*32;i+=256){ int q=i>>5, hh=i&31; qt[q*33+hh] = qbase[q*512 + c*32 + hh]; }
    for (int i=t;i<102*32;i+=256){ int r=i>>5, hh=i&31;
      rt[r*33+hh] = (r<100)? rbase[r*512 + c*32 + hh] : 0.0f; }
    __syncthreads();
    if (act){
      for (int hh=0; hh<32; ++hh){
        float a0=qt[(q0+0)*33+hh], a1=qt[(q0+1)*33+hh], a2=qt[(q0+2)*33+hh], a3=qt[(q0+3)*33+hh];
        #pragma unroll
        for (int j=0;j<6;++j){
          float rv = rt[(r0+j)*33+hh];
          acc[0][j]+=a0*rv; acc[1][j]+=a1*rv; acc[2][j]+=a2*rv; acc[3][j]+=a3*rv;
        }
      }
    }
    __syncthreads();
  }
  if (act){
    #pragma unroll
    for (int i=0;i<4;++i){
      float m = -1e30f;
      for (int j=0;j<6;++j) if (j<nv) m = fmaxf(m, acc[i][j]);
      mqb[(q0+i)*17+tr] = m;
    }
    for (int j=0;j<6;++j) if (j<nv){
      float m = fmaxf(fmaxf(acc[0][j],acc[1][j]), fmaxf(acc[2][j],acc[3][j]));
      mrb[(r0+j)*15+tq] = m;
    }
  }
  __syncthreads();
  if (t<60){ float m=-1e30f; for(int i=0;i<17;++i) m=fmaxf(m,mqb[t*17+i]); uq[t]=tanhf(m); }
  if (t>=64 && t<164){ int r=t-64; float m=-1e30f; for(int i=0;i<15;++i) m=fmaxf(m,mrb[r*15+i]); ur[r]=tanhf(m); }
  __syncthreads();
  if (t==0){ float M=-1e30f; for(int q=0;q<60;++q) M=fmaxf(M,uq[q]); scal[0]=M; }
  if (t==64){ float M=-1e30f; for(int r=0;r<100;++r) M=fmaxf(M,ur[r]); scal[1]=M; }
  __syncthreads();
  if (t<60) uq[t]=expf(uq[t]-scal[0]);
  if (t>=64&&t<164) ur[t-64]=expf(ur[t-64]-scal[1]);
  __syncthreads();
  if (t==0){ float S=0; for(int q=0;q<60;++q)S+=uq[q]; scal[2]=S; }
  if (t==64){ float S=0; for(int r=0;r<100;++r)S+=ur[r]; scal[3]=S; }
  __syncthreads();
  if (t<60) aq[(long)bid*60 + t] = uq[t]/scal[2];
  if (t>=64&&t<164) ar[(long)bid*100 + (t-64)] = ur[t-64]/scal[3];
}

// ---------------------------------------------------------- K6: build pai
__global__ __launch_bounds__(256) void k_pai(
    const float* __restrict__ q_t, const float* __restrict__ r_t,
    const float* __restrict__ aq, const float* __restrict__ ar,
    const float* __restrict__ q_mask, const float* __restrict__ r_mask,
    float* __restrict__ pai)
{
  __shared__ float cf[2];
  long idx = (long)blockIdx.x*256 + threadIdx.x;
  int b = (int)(idx / (LTOT*128));
  int rem = (int)(idx % (LTOT*128));
  int l = rem/128, h4 = rem&127;
  int rem0 = (int)(((long)blockIdx.x*256) % (LTOT*128));
  int l0 = rem0/128;
  if (threadIdx.x < 2){
    int ll = l0 + (int)threadIdx.x;
    float c;
    if (ll < 60){
      float s = aq[(b*4+0)*60+ll]+aq[(b*4+1)*60+ll]+aq[(b*4+2)*60+ll]+aq[(b*4+3)*60+ll];
      c = s * q_mask[b*60+ll] * 0.25f;
    } else {
      int lr = ll-60;
      c = ar[b*400+lr] * r_mask[b*400+lr];
    }
    cf[threadIdx.x] = c;
  }
  __syncthreads();
  float coef = cf[l - l0];
  float4 v;
  if (l < 60) v = ((const float4*)q_t)[((long)(b*60+l)<<7) + h4];
  else        v = ((const float4*)r_t)[((long)(b*400+(l-60))<<7) + h4];
  float4 o; o.x=coef*v.x; o.y=coef*v.y; o.z=coef*v.z; o.w=coef*v.w;
  ((float4*)pai)[((long)(b*460+l)<<7)+h4] = o;
}

// ------------------- K7: proj = pai @ Wqr^T ; e = tanh(...) @ Vr  (hotspot)
__global__ __launch_bounds__(256) void k_proj_e(
    const float* __restrict__ pai, const float* __restrict__ Wqr_w,
    const float* __restrict__ Wqr_b, const float* __restrict__ Wc_w,
    const float* __restrict__ Vr_w, const float* __restrict__ WsS,
    const float* __restrict__ qr_cov, float* __restrict__ e_o)
{
  __shared__ float pt[16*512];
  __shared__ float cov[16];
  __shared__ float wbuf[16*4];
  int bid = blockIdx.x;
  int b = bid / 29, tile = bid % 29;
  int l0 = tile*16, t = threadIdx.x;
  int nrows = (460-l0 < 16)? (460-l0) : 16;
  for (int i=t;i<16*512;i+=256){
    int r = i>>9;
    pt[i] = (r<nrows) ? pai[(long)(b*460+l0+r)*512 + (i&511)] : 0.0f;
  }
  if (t<16) cov[t] = (t<nrows)? qr_cov[b*460+l0+t] : 0.0f;
  __syncthreads();
  float acc0[16]={}, acc1[16]={};
  const float4* w1 = (const float4*)(Wqr_w + (long)t*512);
  const float4* w2 = (const float4*)(Wqr_w + (long)(t+256)*512);
  const float4* pv = (const float4*)pt;
  for (int hp=0;hp<128;++hp){
    float4 a = w1[hp], c = w2[hp];
    #pragma unroll
    for (int r=0;r<16;++r){
      float4 p = pv[r*128+hp];
      acc0[r] += p.x*a.x+p.y*a.y+p.z*a.z+p.w*a.w;
      acc1[r] += p.x*c.x+p.y*c.y+p.z*c.z+p.w*c.w;
    }
  }
  float ws1 = WsS[b*512+t], ws2 = WsS[b*512+256+t];
  float wb1 = Wqr_b[t], wb2 = Wqr_b[256+t];
  float wc1 = Wc_w[t], wc2 = Wc_w[256+t];
  float vr1 = Vr_w[t], vr2 = Vr_w[256+t];
  int lane = t & 63, wid = t >> 6;
  #pragma unroll
  for (int r=0;r<16;++r){
    float v = tanhf(ws1 + acc0[r] + wb1 + cov[r]*wc1)*vr1
            + tanhf(ws2 + acc1[r] + wb2 + cov[r]*wc2)*vr2;
    for (int s=32;s>0;s>>=1) v += __shfl_xor(v, s);
    if (lane==0) wbuf[r*4+wid] = v;
  }
  __syncthreads();
  if (t<nrows) e_o[b*460+l0+t] = wbuf[t*4]+wbuf[t*4+1]+wbuf[t*4+2]+wbuf[t*4+3];
}

// --------- K8: attention softmax + c_t + p_gen + hid (all per-b fused)
__global__ __launch_bounds__(256) void k_attnfin(
    const float* __restrict__ e_i, const float* __restrict__ q_mask, const float* __restrict__ r_mask,
    const float* __restrict__ qr_cov, const float* __restrict__ pai,
    const float* __restrict__ sthat, const float* __restrict__ pg_w, const float* __restrict__ pg_b,
    const float* __restrict__ pv1_w, const float* __restrict__ pv1_b,
    float* __restrict__ a_o, float* __restrict__ ct_ws, float* __restrict__ hid_o,
    float* __restrict__ pgen_o,
    float* __restrict__ out_ct, float* __restrict__ out_a, float* __restrict__ out_cov)
{
  __shared__ float aL[460];
  __shared__ float hst[1024];
  __shared__ float red[8];
  int b = blockIdx.x, t = threadIdx.x;
  int lane = t&63, wid=t>>6;
  float lm = -1e30f;
  for (int i=t;i<460;i+=256){ float v = e_i[b*460+i]; aL[i]=v; lm=fmaxf(lm,v); }
  for (int s=32;s>0;s>>=1) lm = fmaxf(lm, __shfl_xor(lm,s));
  if (lane==0) red[wid]=lm;
  __syncthreads();
  float M = fmaxf(fmaxf(red[0],red[1]),fmaxf(red[2],red[3]));
  __syncthreads();
  float ls=0;
  for (int i=t;i<460;i+=256){
    float mk = (i<60)? q_mask[b*60+i] : r_mask[b*400+i-60];
    float v = expf(aL[i]-M)*mk;
    aL[i]=v; ls+=v;
  }
  for (int s=32;s>0;s>>=1) ls += __shfl_xor(ls,s);
  if (lane==0) red[wid]=ls;
  __syncthreads();
  float S = red[0]+red[1]+red[2]+red[3];
  __syncthreads();
  for (int i=t;i<460;i+=256){
    float v = aL[i]/S; aL[i]=v;
    a_o[b*460+i]=v; out_a[b*460+i]=v; out_cov[b*460+i]=qr_cov[b*460+i]+v;
  }
  for (int i=t;i<512;i+=256) hst[i]=sthat[b*512+i];
  __syncthreads();
  float c1a=0, c2a=0;
  const float* pb = pai + (long)b*460*512;
  for (int l=0;l<460;++l){
    float av = aL[l];
    c1a += av*pb[(long)l*512+t];
    c2a += av*pb[(long)l*512+256+t];
  }
  hst[512+t]=c1a; hst[768+t]=c2a;
  ct_ws[b*512+t]=c1a; ct_ws[b*512+256+t]=c2a;
  out_ct[b*512+t]=c1a; out_ct[b*512+256+t]=c2a;
  __syncthreads();
  float pp = hst[t]*pg_w[t] + hst[256+t]*pg_w[256+t] + hst[512+t]*pg_w[512+t] + hst[768+t]*pg_w[768+t];
  for (int s=32;s>0;s>>=1) pp += __shfl_xor(pp,s);
  if (lane==0) red[wid]=pp;
  __syncthreads();
  float pg = sigm(red[0]+red[1]+red[2]+red[3] + pg_b[0]);
  if (t==0) pgen_o[b]=pg;
  for (int jj=0;jj<2;++jj){
    int h = t + jj*256;
    float acc = pv1_b[h];
    const float* row = pv1_w + (long)h*1024;
    #pragma unroll 4
    for (int d=0;d<1024;++d) acc += hst[d]*row[d];
    hid_o[b*512+h]=acc;
  }
}

// ------------------------------------- K9: vocab logits (GEMV over pv2_w)
__global__ __launch_bounds__(256) void k_logits(
    const float* __restrict__ hid, const float* __restrict__ pv2_w, const float* __restrict__ pv2_b,
    float* __restrict__ logits)
{
  __shared__ float hs[16*512];
  int t = threadIdx.x;
  for (int i=t;i<8192;i+=256) hs[i]=hid[i];
  __syncthreads();
  int v = blockIdx.x*256 + t;
  if (v >= VOCABN) return;
  float acc[16]={};
  const float4* wr = (const float4*)(pv2_w + (long)v*512);
  const float4* hv = (const float4*)hs;
  for (int hp=0;hp<128;++hp){
    float4 w = wr[hp];
    #pragma unroll
    for (int b2=0;b2<16;++b2){
      float4 h = hv[b2*128+hp];
      acc[b2] += w.x*h.x+w.y*h.y+w.z*h.z+w.w*h.w;
    }
  }
  float bias = pv2_b[v];
  #pragma unroll
  for (int b2=0;b2<16;++b2) logits[(long)b2*VOCABN+v] = acc[b2]+bias;
}

// --------------------------- K10: vocab softmax + final dist + scatter-add
__global__ __launch_bounds__(256) void k_final(
    const float* __restrict__ logits, const float* __restrict__ extra_zeros,
    const float* __restrict__ a_ws, const float* __restrict__ pgen,
    const int* __restrict__ bev, float* __restrict__ out)
{
  __shared__ float red[8];
  int b = blockIdx.x, t = threadIdx.x, lane=t&63, wid=t>>6;
  const float* lg = logits + (long)b*VOCABN;
  float lm=-1e30f;
  for (int v=t; v<VOCABN; v+=256) lm=fmaxf(lm, lg[v]);
  for (int s=32;s>0;s>>=1) lm=fmaxf(lm,__shfl_xor(lm,s));
  if (lane==0) red[wid]=lm;
  __syncthreads();
  float M=fmaxf(fmaxf(red[0],red[1]),fmaxf(red[2],red[3]));
  __syncthreads();
  float ls=0;
  for (int v=t;v<VOCABN;v+=256) ls += expf(lg[v]-M);
  for (int s=32;s>0;s>>=1) ls += __shfl_xor(ls,s);
  if (lane==0) red[wid]=ls;
  __syncthreads();
  float S=red[0]+red[1]+red[2]+red[3];
  float pg = pgen[b];
  float sc = pg/S;
  float* ob = out + (long)b*(VOCABN+EXTRAN);
  for (int v=t;v<VOCABN;v+=256) ob[v] = expf(lg[v]-M)*sc;
  if (t<EXTRAN) ob[VOCABN+t] = extra_zeros[b*EXTRAN+t];
  __syncthreads();
  __threadfence();
  float opg = 1.0f-pg;
  for (int l=t;l<460;l+=256){
    atomicAdd(&ob[bev[b*460+l]], opg*a_ws[b*460+l]);
  }
}

extern "C" void kernel_launch(void* const* d_in, const int* in_sizes, int n_in,
                              void* d_out, int out_size, void* d_ws, size_t ws_size,
                              hipStream_t stream)
{
  (void)in_sizes; (void)n_in; (void)out_size; (void)ws_size;
  const float* y_t   = (const float*)d_in[0];
  const float* h0    = (const float*)d_in[1];
  const float* c0    = (const float*)d_in[2];
  const float* c_t_0 = (const float*)d_in[3];
  const float* o_m   = (const float*)d_in[4];
  const float* h_q   = (const float*)d_in[5];
  const float* q_mask= (const float*)d_in[6];
  const float* q_a   = (const float*)d_in[7];
  const float* h_r   = (const float*)d_in[8];
  const float* r_mask= (const float*)d_in[9];
  const float* r_a   = (const float*)d_in[10];
  const float* r_o   = (const float*)d_in[11];
  const float* qr_cov= (const float*)d_in[12];
  const float* extra_zeros=(const float*)d_in[13];
  const float* xc_w  = (const float*)d_in[14];
  const float* xc_b  = (const float*)d_in[15];
  const float* w_ih  = (const float*)d_in[16];
  const float* w_hh  = (const float*)d_in[17];
  const float* b_ih  = (const float*)d_in[18];
  const float* b_hh  = (const float*)d_in[19];
  const float* dsq_w = (const float*)d_in[20];
  const float* dsa_w = (const float*)d_in[21];
  const float* dso_w = (const float*)d_in[22];
  const float* U_w   = (const float*)d_in[23];
  const float* Wc_w  = (const float*)d_in[24];
  const float* Ws_w  = (const float*)d_in[25];
  const float* Wqr_w = (const float*)d_in[26];
  const float* Wqr_b = (const float*)d_in[27];
  const float* Vr_w  = (const float*)d_in[28];
  const float* pg_w  = (const float*)d_in[29];
  const float* pg_b  = (const float*)d_in[30];
  const float* pv1_w = (const float*)d_in[31];
  const float* pv1_b = (const float*)d_in[32];
  const float* pv2_w = (const float*)d_in[33];
  const float* pv2_b = (const float*)d_in[34];
  const int*   bev   = (const int*)d_in[35];

  float* out = (float*)d_out;
  float* out_fd  = out;
  float* out_h1  = out_fd + (size_t)16*50100;
  float* out_c1  = out_h1 + 16*256;
  float* out_ct  = out_c1 + 16*256;
  float* out_a   = out_ct + 16*512;
  float* out_cov = out_a  + 16*460;

  float* ws = (float*)d_ws;
  size_t o = 0;
  float* sthat = ws + o; o += 16*512;
  float* wq    = ws + o; o += 16*8;            // used as [b*5+n]
  float* qat   = ws + o; o += 16*128;
  float* cw    = ws + o; o += 16*32;           // used as [b*20+t]
  float* q_t   = ws + o; o += (size_t)16*60*512;
  float* r_t   = ws + o; o += (size_t)16*400*512;
  float* qU    = ws + o; o += (size_t)16*60*512;
  float* aq    = ws + o; o += 16*4*64;         // used as [(b*4+k)*60+q]
  float* ar    = ws + o; o += 16*4*112;        // used as [(b*4+k)*100+r]
  float* pai   = ws + o; o += (size_t)16*460*512;
  float* WsS   = ws + o; o += 16*512;
  float* e_b   = ws + o; o += 16*512;
  float* a_b   = ws + o; o += 16*512;
  float* ct_b  = ws + o; o += 16*512;
  float* hid_b = ws + o; o += 16*512;
  float* pgen  = ws + o; o += 64;
  float* logits= ws + o; o += (size_t)16*VOCABN;

  hipLaunchKernelGGL(k_lstm, dim3(16), dim3(256), 0, stream,
      y_t,h0,c0,c_t_0,xc_w,xc_b,w_ih,w_hh,b_ih,b_hh, sthat, out_h1, out_c1);
  hipLaunchKernelGGL(k_ds, dim3(16), dim3(128), 0, stream,
      sthat,o_m,q_a,r_a,r_o,dsq_w,dsa_w,dso_w,Ws_w, wq,qat,cw,WsS);
  hipLaunchKernelGGL(k_wsum, dim3(3680), dim3(256), 0, stream,
      h_q,h_r,wq,cw, q_t,r_t);
  hipLaunchKernelGGL(k_qU, dim3(240), dim3(256), 0, stream, q_t, U_w, qU);
  hipLaunchKernelGGL(k_umax, dim3(64), dim3(256), 0, stream, qU, r_t, aq, ar);
  hipLaunchKernelGGL(k_pai, dim3(3680), dim3(256), 0, stream,
      q_t,r_t,aq,ar,q_mask,r_mask, pai);
  hipLaunchKernelGGL(k_proj_e, dim3(464), dim3(256), 0, stream,
      pai,Wqr_w,Wqr_b,Wc_w,Vr_w,WsS,qr_cov, e_b);
  hipLaunchKernelGGL(k_attnfin, dim3(16), dim3(256), 0, stream,
      e_b,q_mask,r_mask,qr_cov,pai,sthat,pg_w,pg_b,pv1_w,pv1_b,
      a_b,ct_b,hid_b,pgen, out_ct,out_a,out_cov);
  hipLaunchKernelGGL(k_logits, dim3(196), dim3(256), 0, stream,
      hid_b, pv2_w, pv2_b, logits);
  hipLaunchKernelGGL(k_final, dim3(16), dim3(256), 0, stream,
      logits, extra_zeros, a_b, pgen, bev, out_fd);
}

// Round 2
// 843.111 us; speedup vs baseline: 1.2779x; 1.2779x over previous
//
#include <hip/hip_runtime.h>
#include <math.h>

#define BB 16
#define H2N 512
#define VOCABN 50000
#define EXTRAN 100
#define LTOT 460
#define EPSF 1e-12f

__device__ __forceinline__ float sigm(float x){ return 1.0f/(1.0f+expf(-x)); }

__device__ __forceinline__ float wred(float v){
  #pragma unroll
  for (int s=32;s>0;s>>=1) v += __shfl_xor(v,s);
  return v;
}
__device__ __forceinline__ float wredmax(float v){
  #pragma unroll
  for (int s=32;s>0;s>>=1) v = fmaxf(v, __shfl_xor(v,s));
  return v;
}

// ======================= K1: fused LSTM + dynamic-select head ==============
// grid 16, block 1024 (16 waves). All GEMVs wave-parallel.
__global__ __launch_bounds__(1024) void k_head(
    const float* __restrict__ y_t, const float* __restrict__ h0, const float* __restrict__ c0,
    const float* __restrict__ c_t_0, const float* __restrict__ o_m,
    const float* __restrict__ q_a, const float* __restrict__ r_a, const float* __restrict__ r_o,
    const float* __restrict__ xc_w, const float* __restrict__ xc_b,
    const float* __restrict__ w_ih, const float* __restrict__ w_hh,
    const float* __restrict__ b_ih, const float* __restrict__ b_hh,
    const float* __restrict__ dsq_w, const float* __restrict__ dsa_w, const float* __restrict__ dso_w,
    const float* __restrict__ Ws_w,
    float* __restrict__ sthat, float* __restrict__ out_h1, float* __restrict__ out_c1,
    float* __restrict__ wq_o, float* __restrict__ cw_o, float* __restrict__ WsS_o)
{
  __shared__ float cat[640], h0s[256], xls[128], gs[1024];
  __shared__ float s[512], om[640], qa_l[640];
  __shared__ float part[1024];
  __shared__ float tq[128], ta[128], to2[128];
  __shared__ float wr2[20], wal[20], sums[4], wql[8], scal[4];
  int b = blockIdx.x, t = threadIdx.x;
  int w = t>>6, lane = t&63;

  // P0: stage inputs
  if (t < 640){
    cat[t] = (t<128) ? y_t[b*128+t] : c_t_0[b*512 + (t-128)];
    om[t]  = o_m[b*640+t];
    qa_l[t]= q_a[b*640+t];
  } else if (t < 896){
    h0s[t-640] = h0[b*256 + (t-640)];
  }
  __syncthreads();

  // P1: xl[128] = cat @ xc_w.T + xc_b   (wave-per-row, lane-strided)
  {
    int j0 = w*8;
    for (int i=0;i<8;++i){
      int j = j0+i;
      const float* row = xc_w + j*640;
      float a = 0.f;
      #pragma unroll
      for (int it=0; it<10; ++it) a += cat[lane+64*it]*row[lane+64*it];
      a = wred(a);
      if (lane==0) xls[j] = a + xc_b[j];
    }
  }
  __syncthreads();

  // P2: gates[1024] = xl @ w_ih.T + h0 @ w_hh.T + biases
  {
    int r0 = w*64;
    for (int i=0;i<64;++i){
      int r = r0+i;
      const float* wi = w_ih + r*128;
      const float* wh = w_hh + r*256;
      float a = xls[lane]*wi[lane] + xls[lane+64]*wi[lane+64];
      #pragma unroll
      for (int it=0; it<4; ++it) a += h0s[lane+64*it]*wh[lane+64*it];
      a = wred(a);
      if (lane==0) gs[r] = a + b_ih[r] + b_hh[r];
    }
  }
  __syncthreads();

  // P3: LSTM cell (gate order i,f,g,o); s = [h1; c1]
  if (t < 256){
    float c1v = sigm(gs[256+t])*c0[b*256+t] + sigm(gs[t])*tanhf(gs[512+t]);
    float h1v = sigm(gs[768+t])*tanhf(c1v);
    s[t] = h1v; s[256+t] = c1v;
    sthat[b*512+t] = h1v; sthat[b*512+256+t] = c1v;
    out_h1[b*256+t] = h1v; out_c1[b*256+t] = c1v;
  }
  __syncthreads();

  // P4: tmpq[128] = s @ dsq_w  (split-d: 8 segs x 64 d, coalesced over j)
  {
    int j = t&127, seg = t>>7, d0 = seg*64;
    float a = 0.f;
    #pragma unroll 8
    for (int it=0; it<64; ++it){ int d = d0+it; a += s[d]*dsq_w[d*128+j]; }
    part[seg*128+j] = a;
  }
  __syncthreads();
  if (t < 128){
    float a = 0.f;
    #pragma unroll
    for (int sg=0; sg<8; ++sg) a += part[sg*128+t];
    tq[t] = a;
  }
  __syncthreads();

  // P5: wr_q[5] = tanh(tmpq . q_a[n]); normalize; qat -> tq (reuse)
  if (w < 5){
    float p = tq[lane]*qa_l[w*128+lane] + tq[lane+64]*qa_l[w*128+64+lane];
    p = wred(p);
    if (lane==0) wr2[w] = tanhf(p);
  }
  __syncthreads();
  if (t==0){ float sm=EPSF; for(int n=0;n<5;++n) sm+=wr2[n]; scal[0]=sm; }
  __syncthreads();
  if (t<5){ float v = wr2[t]/scal[0]; wql[t]=v; wq_o[b*5+t]=v; }
  __syncthreads();
  if (t<128){
    float a=0.f;
    #pragma unroll
    for (int n=0;n<5;++n) a += wql[n]*qa_l[n*128+t];
    tq[t]=a;                       // tq now holds q_a_t (qat)
  }
  __syncthreads();

  // P6: tmpa[128] = [s; qat] @ dsa_w  (640 dims, 8 segs x 80)
  {
    int j = t&127, seg = t>>7, d0 = seg*80;
    float a = 0.f;
    for (int it=0; it<80; ++it){
      int d = d0+it;
      float sv = (d<512) ? s[d] : tq[d-512];
      a += sv*dsa_w[d*128+j];
    }
    part[seg*128+j] = a;
  }
  __syncthreads();
  if (t < 128){
    float a=0.f;
    #pragma unroll
    for (int sg=0; sg<8; ++sg) a += part[sg*128+t];
    ta[t]=a;
  }
  __syncthreads();

  // P7: wr_a[20], normalize per k
  for (int oo=w; oo<20; oo+=16){
    const float* ra = r_a + ((long)(b*4 + oo/5)*5 + (oo%5))*128;
    float p = ta[lane]*ra[lane] + ta[lane+64]*ra[lane+64];
    p = wred(p);
    if (lane==0) wr2[oo] = tanhf(p);
  }
  __syncthreads();
  if (t<4){ float sm=EPSF; for(int n=0;n<5;++n) sm+=wr2[t*5+n]; sums[t]=sm; }
  __syncthreads();
  if (t<20) wal[t] = wr2[t]/sums[t/5];
  __syncthreads();

  // P8: tmpo[128] = [s; om] @ dso_w  (1152 dims, 8 segs x 144)
  {
    int j = t&127, seg = t>>7, d0 = seg*144;
    float a = 0.f;
    for (int it=0; it<144; ++it){
      int d = d0+it;
      float sv = (d<512) ? s[d] : om[d-512];
      a += sv*dso_w[d*128+j];
    }
    part[seg*128+j] = a;
  }
  __syncthreads();
  if (t < 128){
    float a=0.f;
    #pragma unroll
    for (int sg=0; sg<8; ++sg) a += part[sg*128+t];
    to2[t]=a;
  }
  __syncthreads();

  // P9: wr_o[20]; cw = wa + wo
  for (int oo=w; oo<20; oo+=16){
    const float* ro = r_o + ((long)(b*4 + oo/5)*5 + (oo%5))*128;
    float p = to2[lane]*ro[lane] + to2[lane+64]*ro[lane+64];
    p = wred(p);
    if (lane==0) wr2[oo] = tanhf(p);
  }
  __syncthreads();
  if (t<4){ float sm=EPSF; for(int n=0;n<5;++n) sm+=wr2[t*5+n]; sums[t]=sm; }
  __syncthreads();
  if (t<20) cw_o[b*20+t] = wal[t] + wr2[t]/sums[t/5];

  // P10: WsS[512] = s @ Ws_w.T (wave-per-row, lane-strided coalesced)
  for (int i=0;i<32;++i){
    int h = w*32 + i;
    const float* row = Ws_w + (long)h*512;
    float a = 0.f;
    #pragma unroll
    for (int it=0; it<8; ++it) a += s[lane+64*it]*row[lane+64*it];
    a = wred(a);
    if (lane==0) WsS_o[b*512+h] = a;
  }
}

// =================== K2: q_t / r_t weighted sums (flat float4) =============
#define NQT4 (BB*60*128)
__global__ __launch_bounds__(256) void k_wsum(
    const float* __restrict__ h_q, const float* __restrict__ h_r,
    const float* __restrict__ wq, const float* __restrict__ cw,
    float* __restrict__ q_t, float* __restrict__ r_t)
{
  __shared__ float cf[5];
  long idx = (long)blockIdx.x*256 + threadIdx.x;
  if (blockIdx.x < 480) {
    int b = (int)(idx / (60*128));
    if (threadIdx.x < 5) cf[threadIdx.x] = wq[b*5+threadIdx.x];
    __syncthreads();
    int rem = (int)(idx % (60*128));
    int l = rem/128, h4 = rem&127;
    const float4* src = (const float4*)h_q;
    float4 acc = {0,0,0,0};
    #pragma unroll
    for (int n=0;n<5;++n){
      float4 v = src[(((long)(b*5+n)*60 + l)<<7) + h4];
      float ww = cf[n];
      acc.x += ww*v.x; acc.y += ww*v.y; acc.z += ww*v.z; acc.w += ww*v.w;
    }
    ((float4*)q_t)[((long)(b*60+l)<<7) + h4] = acc;
  } else {
    long j = idx - NQT4;
    int bk = (int)(j / (100*128));
    if (threadIdx.x < 5) cf[threadIdx.x] = cw[bk*5+threadIdx.x];
    __syncthreads();
    int rem = (int)(j % (100*128));
    int l = rem/128, h4 = rem&127;
    const float4* src = (const float4*)h_r;
    float4 acc = {0,0,0,0};
    #pragma unroll
    for (int n=0;n<5;++n){
      float4 v = src[(((long)(bk*5+n)*100 + l)<<7) + h4];
      float ww = cf[n];
      acc.x += ww*v.x; acc.y += ww*v.y; acc.z += ww*v.z; acc.w += ww*v.w;
    }
    ((float4*)r_t)[((long)(bk*100+l)<<7) + h4] = acc;
  }
}

// ========================= K3: qU = q_t @ U_w^T ============================
__global__ __launch_bounds__(256) void k_qU(
    const float* __restrict__ q_t, const float* __restrict__ U_w, float* __restrict__ qU)
{
  __shared__ float qt[4*512];
  int bid = blockIdx.x; int b = bid/15, tile = bid%15, q0 = tile*4, t = threadIdx.x;
  for (int i=t;i<2048;i+=256) qt[i] = q_t[(long)(b*60+q0)*512 + i];
  __syncthreads();
  float acc[4][2] = {};
  const float4* w1 = (const float4*)(U_w + (long)t*512);
  const float4* w2 = (const float4*)(U_w + (long)(t+256)*512);
  const float4* qv = (const float4*)qt;
  for (int hp=0; hp<128; ++hp){
    float4 a = w1[hp], c = w2[hp];
    #pragma unroll
    for (int qi=0; qi<4; ++qi){
      float4 p = qv[qi*128+hp];
      acc[qi][0] += p.x*a.x+p.y*a.y+p.z*a.z+p.w*a.w;
      acc[qi][1] += p.x*c.x+p.y*c.y+p.z*c.z+p.w*c.w;
    }
  }
  #pragma unroll
  for (int qi=0;qi<4;++qi){
    qU[(long)(b*60+q0+qi)*512 + t]       = acc[qi][0];
    qU[(long)(b*60+q0+qi)*512 + 256 + t] = acc[qi][1];
  }
}

// ========== K4: U-max over tanh(qU . r_t^T) + alpha softmaxes ==============
__global__ __launch_bounds__(256) void k_umax(
    const float* __restrict__ qU, const float* __restrict__ r_t,
    float* __restrict__ aq, float* __restrict__ ar)
{
  __shared__ float qt[60*33];
  __shared__ float rt[102*33];
  __shared__ float mqb[60*17];
  __shared__ float mrb[100*15];
  __shared__ float uq[60], ur[100], scal[4];
  int bid = blockIdx.x; int b = bid>>2, k = bid&3, t = threadIdx.x;
  bool act = t < 255;
  int tq = t/17, tr = t%17;
  int q0 = tq*4, r0 = tr*6;
  int nv = (r0+6<=100)? 6 : (100-r0);
  float acc[4][6] = {};
  const float* qbase = qU + (long)b*60*512;
  const float* rbase = r_t + (long)(b*4+k)*100*512;
  for (int c=0;c<16;++c){
    for (int i=t;i<60*32;i+=256){ int q=i>>5, hh=i&31; qt[q*33+hh] = qbase[q*512 + c*32 + hh]; }
    for (int i=t;i<102*32;i+=256){ int r=i>>5, hh=i&31;
      rt[r*33+hh] = (r<100)? rbase[r*512 + c*32 + hh] : 0.0f; }
    __syncthreads();
    if (act){
      for (int hh=0; hh<32; ++hh){
        float a0=qt[(q0+0)*33+hh], a1=qt[(q0+1)*33+hh], a2=qt[(q0+2)*33+hh], a3=qt[(q0+3)*33+hh];
        #pragma unroll
        for (int j=0;j<6;++j){
          float rv = rt[(r0+j)*33+hh];
          acc[0][j]+=a0*rv; acc[1][j]+=a1*rv; acc[2][j]+=a2*rv; acc[3][j]+=a3*rv;
        }
      }
    }
    __syncthreads();
  }
  if (act){
    #pragma unroll
    for (int i=0;i<4;++i){
      float m = -1e30f;
      for (int j=0;j<6;++j) if (j<nv) m = fmaxf(m, acc[i][j]);
      mqb[(q0+i)*17+tr] = m;
    }
    for (int j=0;j<6;++j) if (j<nv){
      float m = fmaxf(fmaxf(acc[0][j],acc[1][j]), fmaxf(acc[2][j],acc[3][j]));
      mrb[(r0+j)*15+tq] = m;
    }
  }
  __syncthreads();
  if (t<60){ float m=-1e30f; for(int i=0;i<17;++i) m=fmaxf(m,mqb[t*17+i]); uq[t]=tanhf(m); }
  if (t>=64 && t<164){ int r=t-64; float m=-1e30f; for(int i=0;i<15;++i) m=fmaxf(m,mrb[r*15+i]); ur[r]=tanhf(m); }
  __syncthreads();
  if (t==0){ float M=-1e30f; for(int q=0;q<60;++q) M=fmaxf(M,uq[q]); scal[0]=M; }
  if (t==64){ float M=-1e30f; for(int r=0;r<100;++r) M=fmaxf(M,ur[r]); scal[1]=M; }
  __syncthreads();
  if (t<60) uq[t]=expf(uq[t]-scal[0]);
  if (t>=64&&t<164) ur[t-64]=expf(ur[t-64]-scal[1]);
  __syncthreads();
  if (t==0){ float S=0; for(int q=0;q<60;++q)S+=uq[q]; scal[2]=S; }
  if (t==64){ float S=0; for(int r=0;r<100;++r)S+=ur[r]; scal[3]=S; }
  __syncthreads();
  if (t<60) aq[(long)bid*60 + t] = uq[t]/scal[2];
  if (t>=64&&t<164) ar[(long)bid*100 + (t-64)] = ur[t-64]/scal[3];
}

// ======== K5: e = tanh(WsS + pai@Wqr^T + b + cov*Wc) @ Vr  (pai fused) =====
__global__ __launch_bounds__(256) void k_proj_e(
    const float* __restrict__ q_t, const float* __restrict__ r_t,
    const float* __restrict__ aq, const float* __restrict__ ar,
    const float* __restrict__ q_mask, const float* __restrict__ r_mask,
    const float* __restrict__ Wqr_w, const float* __restrict__ Wqr_b,
    const float* __restrict__ Wc_w, const float* __restrict__ Vr_w,
    const float* __restrict__ WsS, const float* __restrict__ qr_cov,
    float* __restrict__ e_o)
{
  __shared__ float pt[16*512];
  __shared__ float cov[16], coef[16];
  __shared__ float wbuf[16*4];
  int bid = blockIdx.x;
  int b = bid / 29, tile = bid % 29;
  int l0 = tile*16, t = threadIdx.x;
  int nrows = (460-l0 < 16)? (460-l0) : 16;
  if (t<16){
    float pc=0.f, cv=0.f;
    if (t<nrows){
      int l = l0+t;
      cv = qr_cov[b*460+l];
      if (l < 60){
        float s4 = aq[(b*4+0)*60+l]+aq[(b*4+1)*60+l]+aq[(b*4+2)*60+l]+aq[(b*4+3)*60+l];
        pc = s4 * q_mask[b*60+l] * 0.25f;
      } else {
        pc = ar[b*400+(l-60)] * r_mask[b*400+(l-60)];
      }
    }
    coef[t]=pc; cov[t]=cv;
  }
  __syncthreads();
  for (int i=t;i<16*512;i+=256){
    int r = i>>9, d = i&511;
    float v = 0.f;
    if (r < nrows){
      int l = l0+r;
      v = (l<60) ? q_t[((long)(b*60+l)<<9)+d] : r_t[((long)(b*400+(l-60))<<9)+d];
      v *= coef[r];
    }
    pt[i]=v;
  }
  __syncthreads();
  float acc0[16]={}, acc1[16]={};
  const float4* w1 = (const float4*)(Wqr_w + (long)t*512);
  const float4* w2 = (const float4*)(Wqr_w + (long)(t+256)*512);
  const float4* pv = (const float4*)pt;
  for (int hp=0;hp<128;++hp){
    float4 a = w1[hp], c = w2[hp];
    #pragma unroll
    for (int r=0;r<16;++r){
      float4 p = pv[r*128+hp];
      acc0[r] += p.x*a.x+p.y*a.y+p.z*a.z+p.w*a.w;
      acc1[r] += p.x*c.x+p.y*c.y+p.z*c.z+p.w*c.w;
    }
  }
  float ws1 = WsS[b*512+t], ws2 = WsS[b*512+256+t];
  float wb1 = Wqr_b[t], wb2 = Wqr_b[256+t];
  float wc1 = Wc_w[t], wc2 = Wc_w[256+t];
  float vr1 = Vr_w[t], vr2 = Vr_w[256+t];
  int lane = t & 63, wid = t >> 6;
  #pragma unroll
  for (int r=0;r<16;++r){
    float v = tanhf(ws1 + acc0[r] + wb1 + cov[r]*wc1)*vr1
            + tanhf(ws2 + acc1[r] + wb2 + cov[r]*wc2)*vr2;
    v = wred(v);
    if (lane==0) wbuf[r*4+wid] = v;
  }
  __syncthreads();
  if (t<nrows) e_o[b*460+l0+t] = wbuf[t*4]+wbuf[t*4+1]+wbuf[t*4+2]+wbuf[t*4+3];
}

// === K6: attn softmax + c_t + p_gen + hid (grid 16, block 1024, pai fused) =
__global__ __launch_bounds__(1024) void k_attnfin(
    const float* __restrict__ e_i, const float* __restrict__ q_mask, const float* __restrict__ r_mask,
    const float* __restrict__ qr_cov,
    const float* __restrict__ q_t, const float* __restrict__ r_t,
    const float* __restrict__ aq, const float* __restrict__ ar,
    const float* __restrict__ sthat, const float* __restrict__ pg_w, const float* __restrict__ pg_b,
    const float* __restrict__ pv1_w, const float* __restrict__ pv1_b,
    float* __restrict__ a_o, float* __restrict__ hid_o, float* __restrict__ pgen_o,
    float* __restrict__ out_ct, float* __restrict__ out_a, float* __restrict__ out_cov)
{
  __shared__ float aL[460], coefL[460], hst[1024], parts[1024], red[16];
  int b = blockIdx.x, t = threadIdx.x, w = t>>6, lane = t&63;
  if (t<512) hst[t] = sthat[b*512+t];
  float ev = (t<460) ? e_i[b*460+t] : -1e30f;
  float m = wredmax(ev);
  if (lane==0) red[w]=m;
  __syncthreads();
  float M=-1e30f;
  #pragma unroll
  for (int i=0;i<16;++i) M=fmaxf(M,red[i]);
  __syncthreads();
  float x = 0.f;
  float mk = 0.f;
  if (t<460){
    mk = (t<60) ? q_mask[b*60+t] : r_mask[b*400+(t-60)];
    x = expf(ev-M)*mk;
  }
  float sr = wred(x);
  if (lane==0) red[w]=sr;
  __syncthreads();
  float S=0.f;
  #pragma unroll
  for (int i=0;i<16;++i) S+=red[i];
  __syncthreads();
  if (t<460){
    float v = x/S;
    aL[t]=v;
    a_o[b*460+t]=v; out_a[b*460+t]=v; out_cov[b*460+t]=qr_cov[b*460+t]+v;
    float pc;
    if (t<60){
      float s4 = aq[(b*4+0)*60+t]+aq[(b*4+1)*60+t]+aq[(b*4+2)*60+t]+aq[(b*4+3)*60+t];
      pc = s4 * q_mask[b*60+t] * 0.25f;
    } else {
      pc = ar[b*400+(t-60)] * r_mask[b*400+(t-60)];
    }
    coefL[t]=v*pc;
  }
  __syncthreads();
  // c_t[512]: split l-range into 2 segs of 230
  {
    int h = t&511, seg = t>>9;
    float a = 0.f;
    int lA = seg*230, lB = lA+230;
    for (int l=lA; l<lB; ++l){
      const float* src = (l<60) ? (q_t + ((long)(b*60+l)<<9))
                                : (r_t + ((long)(b*400+(l-60))<<9));
      a += coefL[l]*src[h];
    }
    parts[t]=a;
  }
  __syncthreads();
  if (t<512){
    float ct = parts[t]+parts[512+t];
    hst[512+t]=ct;
    out_ct[b*512+t]=ct;
  }
  __syncthreads();
  // p_gen
  {
    float p = hst[t]*pg_w[t];
    p = wred(p);
    if (lane==0) red[w]=p;
  }
  __syncthreads();
  if (t==0){
    float pp = pg_b[0];
    #pragma unroll
    for (int i=0;i<16;++i) pp+=red[i];
    pgen_o[b]=sigm(pp);
  }
  // hid[512] = hst @ pv1_w.T + b  (wave-per-row, lane-strided)
  for (int i=0;i<32;++i){
    int h = w*32+i;
    const float* row = pv1_w + (long)h*1024;
    float a = 0.f;
    #pragma unroll
    for (int it=0; it<16; ++it) a += hst[lane+64*it]*row[lane+64*it];
    a = wred(a);
    if (lane==0) hid_o[b*512+h] = a + pv1_b[h];
  }
}

// ================== K7: vocab logits (4 threads per row) ===================
__global__ __launch_bounds__(256) void k_logits(
    const float* __restrict__ hid, const float* __restrict__ pv2_w, const float* __restrict__ pv2_b,
    float* __restrict__ logits)
{
  __shared__ float hs[16*512];
  int t = threadIdx.x;
  for (int i=t;i<8192;i+=256) hs[i]=hid[i];
  __syncthreads();
  int vl = t>>2, seg = t&3;
  long v = (long)blockIdx.x*64 + vl;
  float acc[16]={};
  if (v < VOCABN){
    const float4* wr = (const float4*)(pv2_w + v*512 + seg*128);
    const float4* hv = ((const float4*)hs) + seg*32;
    for (int i=0;i<32;++i){
      int j = (i + seg*2)&31;          // stagger: avoids 4-way LDS bank conflict
      float4 wv = wr[j];
      #pragma unroll
      for (int b2=0;b2<16;++b2){
        float4 h = hv[b2*128+j];
        acc[b2] += wv.x*h.x+wv.y*h.y+wv.z*h.z+wv.w*h.w;
      }
    }
  }
  #pragma unroll
  for (int b2=0;b2<16;++b2){
    acc[b2] += __shfl_xor(acc[b2],1);
    acc[b2] += __shfl_xor(acc[b2],2);
  }
  if (seg==0 && v < VOCABN){
    float bias = pv2_b[v];
    #pragma unroll
    for (int b2=0;b2<16;++b2) logits[(long)b2*VOCABN+v] = acc[b2]+bias;
  }
}

// ============ K8: vocab softmax + final dist + scatter-add =================
__global__ __launch_bounds__(1024) void k_final(
    const float* __restrict__ logits, const float* __restrict__ extra_zeros,
    const float* __restrict__ a_ws, const float* __restrict__ pgen,
    const int* __restrict__ bev, float* __restrict__ out)
{
  __shared__ float red[16];
  int b = blockIdx.x, t = threadIdx.x, w=t>>6, lane=t&63;
  const float* lg = logits + (long)b*VOCABN;
  float lm=-1e30f;
  for (int v=t; v<VOCABN; v+=1024) lm=fmaxf(lm, lg[v]);
  lm = wredmax(lm);
  if (lane==0) red[w]=lm;
  __syncthreads();
  float M=-1e30f;
  #pragma unroll
  for (int i=0;i<16;++i) M=fmaxf(M,red[i]);
  __syncthreads();
  float ls=0;
  for (int v=t;v<VOCABN;v+=1024) ls += expf(lg[v]-M);
  ls = wred(ls);
  if (lane==0) red[w]=ls;
  __syncthreads();
  float S=0;
  #pragma unroll
  for (int i=0;i<16;++i) S+=red[i];
  float pg = pgen[b];
  float sc = pg/S;
  float* ob = out + (long)b*(VOCABN+EXTRAN);
  for (int v=t;v<VOCABN;v+=1024) ob[v] = expf(lg[v]-M)*sc;
  if (t<EXTRAN) ob[VOCABN+t] = extra_zeros[b*EXTRAN+t];
  __syncthreads();
  float opg = 1.0f-pg;
  for (int l=t;l<460;l+=1024){
    atomicAdd(&ob[bev[b*460+l]], opg*a_ws[b*460+l]);
  }
}

extern "C" void kernel_launch(void* const* d_in, const int* in_sizes, int n_in,
                              void* d_out, int out_size, void* d_ws, size_t ws_size,
                              hipStream_t stream)
{
  (void)in_sizes; (void)n_in; (void)out_size; (void)ws_size;
  const float* y_t   = (const float*)d_in[0];
  const float* h0    = (const float*)d_in[1];
  const float* c0    = (const float*)d_in[2];
  const float* c_t_0 = (const float*)d_in[3];
  const float* o_m   = (const float*)d_in[4];
  const float* h_q   = (const float*)d_in[5];
  const float* q_mask= (const float*)d_in[6];
  const float* q_a   = (const float*)d_in[7];
  const float* h_r   = (const float*)d_in[8];
  const float* r_mask= (const float*)d_in[9];
  const float* r_a   = (const float*)d_in[10];
  const float* r_o   = (const float*)d_in[11];
  const float* qr_cov= (const float*)d_in[12];
  const float* extra_zeros=(const float*)d_in[13];
  const float* xc_w  = (const float*)d_in[14];
  const float* xc_b  = (const float*)d_in[15];
  const float* w_ih  = (const float*)d_in[16];
  const float* w_hh  = (const float*)d_in[17];
  const float* b_ih  = (const float*)d_in[18];
  const float* b_hh  = (const float*)d_in[19];
  const float* dsq_w = (const float*)d_in[20];
  const float* dsa_w = (const float*)d_in[21];
  const float* dso_w = (const float*)d_in[22];
  const float* U_w   = (const float*)d_in[23];
  const float* Wc_w  = (const float*)d_in[24];
  const float* Ws_w  = (const float*)d_in[25];
  const float* Wqr_w = (const float*)d_in[26];
  const float* Wqr_b = (const float*)d_in[27];
  const float* Vr_w  = (const float*)d_in[28];
  const float* pg_w  = (const float*)d_in[29];
  const float* pg_b  = (const float*)d_in[30];
  const float* pv1_w = (const float*)d_in[31];
  const float* pv1_b = (const float*)d_in[32];
  const float* pv2_w = (const float*)d_in[33];
  const float* pv2_b = (const float*)d_in[34];
  const int*   bev   = (const int*)d_in[35];

  float* out = (float*)d_out;
  float* out_fd  = out;
  float* out_h1  = out_fd + (size_t)16*(VOCABN+EXTRAN);
  float* out_c1  = out_h1 + 16*256;
  float* out_ct  = out_c1 + 16*256;
  float* out_a   = out_ct + 16*512;
  float* out_cov = out_a  + 16*460;

  float* ws = (float*)d_ws;
  size_t o = 0;
  float* sthat = ws + o; o += 16*512;
  float* wq    = ws + o; o += 16*8;
  float* cw    = ws + o; o += 16*32;
  float* WsS   = ws + o; o += 16*512;
  float* q_t   = ws + o; o += (size_t)16*60*512;
  float* r_t   = ws + o; o += (size_t)16*400*512;
  float* qU    = ws + o; o += (size_t)16*60*512;
  float* aq    = ws + o; o += 16*4*64;
  float* ar    = ws + o; o += 16*4*112;
  float* e_b   = ws + o; o += 16*512;
  float* a_b   = ws + o; o += 16*512;
  float* hid_b = ws + o; o += 16*512;
  float* pgen  = ws + o; o += 64;
  float* logits= ws + o; o += (size_t)16*VOCABN;

  hipLaunchKernelGGL(k_head, dim3(16), dim3(1024), 0, stream,
      y_t,h0,c0,c_t_0,o_m,q_a,r_a,r_o,
      xc_w,xc_b,w_ih,w_hh,b_ih,b_hh,dsq_w,dsa_w,dso_w,Ws_w,
      sthat,out_h1,out_c1, wq,cw,WsS);
  hipLaunchKernelGGL(k_wsum, dim3(3680), dim3(256), 0, stream,
      h_q,h_r,wq,cw, q_t,r_t);
  hipLaunchKernelGGL(k_qU, dim3(240), dim3(256), 0, stream, q_t, U_w, qU);
  hipLaunchKernelGGL(k_umax, dim3(64), dim3(256), 0, stream, qU, r_t, aq, ar);
  hipLaunchKernelGGL(k_proj_e, dim3(464), dim3(256), 0, stream,
      q_t,r_t,aq,ar,q_mask,r_mask,Wqr_w,Wqr_b,Wc_w,Vr_w,WsS,qr_cov, e_b);
  hipLaunchKernelGGL(k_attnfin, dim3(16), dim3(1024), 0, stream,
      e_b,q_mask,r_mask,qr_cov,q_t,r_t,aq,ar,sthat,pg_w,pg_b,pv1_w,pv1_b,
      a_b,hid_b,pgen, out_ct,out_a,out_cov);
  hipLaunchKernelGGL(k_logits, dim3((VOCABN+63)/64), dim3(256), 0, stream,
      hid_b, pv2_w, pv2_b, logits);
  hipLaunchKernelGGL(k_final, dim3(16), dim3(1024), 0, stream,
      logits, extra_zeros, a_b, pgen, bev, out_fd);
}

// Round 3
// 775.752 us; speedup vs baseline: 1.3888x; 1.0868x over previous
//
#include <hip/hip_runtime.h>
#include <math.h>

#define BB 16
#define H2N 512
#define VOCABN 50000
#define EXTRAN 100
#define LTOT 460
#define EPSF 1e-12f

__device__ __forceinline__ float sigm(float x){ return 1.0f/(1.0f+expf(-x)); }

__device__ __forceinline__ float wred(float v){
  #pragma unroll
  for (int s=32;s>0;s>>=1) v += __shfl_xor(v,s);
  return v;
}
__device__ __forceinline__ float wredmax(float v){
  #pragma unroll
  for (int s=32;s>0;s>>=1) v = fmaxf(v, __shfl_xor(v,s));
  return v;
}

// ============ K0: transpose U_w and Wqr_w (512x512 each) into ws ===========
__global__ __launch_bounds__(256) void k_tr(
    const float* __restrict__ A, const float* __restrict__ B,
    float* __restrict__ AT, float* __restrict__ BT)
{
  __shared__ float tile[32][33];
  int m = blockIdx.x >> 8;
  int tid = blockIdx.x & 255;
  int tx = tid & 15, ty = tid >> 4;
  const float* src = m ? B : A;
  float* dst = m ? BT : AT;
  int t = threadIdx.x;
  int lx = t & 31, ly = t >> 5;
  int r0 = ty*32, c0 = tx*32;
  #pragma unroll
  for (int i=0;i<4;++i)
    tile[ly+8*i][lx] = src[(long)(r0+ly+8*i)*512 + c0+lx];
  __syncthreads();
  #pragma unroll
  for (int i=0;i<4;++i)
    dst[(long)(c0+ly+8*i)*512 + r0+lx] = tile[lx][ly+8*i];
}

// ======================= K1: fused LSTM + dynamic-select head ==============
__global__ __launch_bounds__(1024) void k_head(
    const float* __restrict__ y_t, const float* __restrict__ h0, const float* __restrict__ c0,
    const float* __restrict__ c_t_0, const float* __restrict__ o_m,
    const float* __restrict__ q_a, const float* __restrict__ r_a, const float* __restrict__ r_o,
    const float* __restrict__ xc_w, const float* __restrict__ xc_b,
    const float* __restrict__ w_ih, const float* __restrict__ w_hh,
    const float* __restrict__ b_ih, const float* __restrict__ b_hh,
    const float* __restrict__ dsq_w, const float* __restrict__ dsa_w, const float* __restrict__ dso_w,
    const float* __restrict__ Ws_w,
    float* __restrict__ sthat, float* __restrict__ out_h1, float* __restrict__ out_c1,
    float* __restrict__ wq_o, float* __restrict__ cw_o, float* __restrict__ WsS_o)
{
  __shared__ float cat[640], h0s[256], xls[128], gs[1024];
  __shared__ float s[512], om[640], qa_l[640];
  __shared__ float part[1024];
  __shared__ float tq[128], ta[128], to2[128];
  __shared__ float wr2[20], wal[20], sums[4], wql[8], scal[4];
  int b = blockIdx.x, t = threadIdx.x;
  int w = t>>6, lane = t&63;

  if (t < 640){
    cat[t] = (t<128) ? y_t[b*128+t] : c_t_0[b*512 + (t-128)];
    om[t]  = o_m[b*640+t];
    qa_l[t]= q_a[b*640+t];
  } else if (t < 896){
    h0s[t-640] = h0[b*256 + (t-640)];
  }
  __syncthreads();

  {
    int j0 = w*8;
    for (int i=0;i<8;++i){
      int j = j0+i;
      const float* row = xc_w + j*640;
      float a = 0.f;
      #pragma unroll
      for (int it=0; it<10; ++it) a += cat[lane+64*it]*row[lane+64*it];
      a = wred(a);
      if (lane==0) xls[j] = a + xc_b[j];
    }
  }
  __syncthreads();

  {
    int r0 = w*64;
    for (int i=0;i<64;++i){
      int r = r0+i;
      const float* wi = w_ih + r*128;
      const float* wh = w_hh + r*256;
      float a = xls[lane]*wi[lane] + xls[lane+64]*wi[lane+64];
      #pragma unroll
      for (int it=0; it<4; ++it) a += h0s[lane+64*it]*wh[lane+64*it];
      a = wred(a);
      if (lane==0) gs[r] = a + b_ih[r] + b_hh[r];
    }
  }
  __syncthreads();

  if (t < 256){
    float c1v = sigm(gs[256+t])*c0[b*256+t] + sigm(gs[t])*tanhf(gs[512+t]);
    float h1v = sigm(gs[768+t])*tanhf(c1v);
    s[t] = h1v; s[256+t] = c1v;
    sthat[b*512+t] = h1v; sthat[b*512+256+t] = c1v;
    out_h1[b*256+t] = h1v; out_c1[b*256+t] = c1v;
  }
  __syncthreads();

  {
    int j = t&127, seg = t>>7, d0 = seg*64;
    float a = 0.f;
    #pragma unroll 8
    for (int it=0; it<64; ++it){ int d = d0+it; a += s[d]*dsq_w[d*128+j]; }
    part[seg*128+j] = a;
  }
  __syncthreads();
  if (t < 128){
    float a = 0.f;
    #pragma unroll
    for (int sg=0; sg<8; ++sg) a += part[sg*128+t];
    tq[t] = a;
  }
  __syncthreads();

  if (w < 5){
    float p = tq[lane]*qa_l[w*128+lane] + tq[lane+64]*qa_l[w*128+64+lane];
    p = wred(p);
    if (lane==0) wr2[w] = tanhf(p);
  }
  __syncthreads();
  if (t==0){ float sm=EPSF; for(int n=0;n<5;++n) sm+=wr2[n]; scal[0]=sm; }
  __syncthreads();
  if (t<5){ float v = wr2[t]/scal[0]; wql[t]=v; wq_o[b*5+t]=v; }
  __syncthreads();
  if (t<128){
    float a=0.f;
    #pragma unroll
    for (int n=0;n<5;++n) a += wql[n]*qa_l[n*128+t];
    tq[t]=a;
  }
  __syncthreads();

  {
    int j = t&127, seg = t>>7, d0 = seg*80;
    float a = 0.f;
    for (int it=0; it<80; ++it){
      int d = d0+it;
      float sv = (d<512) ? s[d] : tq[d-512];
      a += sv*dsa_w[d*128+j];
    }
    part[seg*128+j] = a;
  }
  __syncthreads();
  if (t < 128){
    float a=0.f;
    #pragma unroll
    for (int sg=0; sg<8; ++sg) a += part[sg*128+t];
    ta[t]=a;
  }
  __syncthreads();

  for (int oo=w; oo<20; oo+=16){
    const float* ra = r_a + ((long)(b*4 + oo/5)*5 + (oo%5))*128;
    float p = ta[lane]*ra[lane] + ta[lane+64]*ra[lane+64];
    p = wred(p);
    if (lane==0) wr2[oo] = tanhf(p);
  }
  __syncthreads();
  if (t<4){ float sm=EPSF; for(int n=0;n<5;++n) sm+=wr2[t*5+n]; sums[t]=sm; }
  __syncthreads();
  if (t<20) wal[t] = wr2[t]/sums[t/5];
  __syncthreads();

  {
    int j = t&127, seg = t>>7, d0 = seg*144;
    float a = 0.f;
    for (int it=0; it<144; ++it){
      int d = d0+it;
      float sv = (d<512) ? s[d] : om[d-512];
      a += sv*dso_w[d*128+j];
    }
    part[seg*128+j] = a;
  }
  __syncthreads();
  if (t < 128){
    float a=0.f;
    #pragma unroll
    for (int sg=0; sg<8; ++sg) a += part[sg*128+t];
    to2[t]=a;
  }
  __syncthreads();

  for (int oo=w; oo<20; oo+=16){
    const float* ro = r_o + ((long)(b*4 + oo/5)*5 + (oo%5))*128;
    float p = to2[lane]*ro[lane] + to2[lane+64]*ro[lane+64];
    p = wred(p);
    if (lane==0) wr2[oo] = tanhf(p);
  }
  __syncthreads();
  if (t<4){ float sm=EPSF; for(int n=0;n<5;++n) sm+=wr2[t*5+n]; sums[t]=sm; }
  __syncthreads();
  if (t<20) cw_o[b*20+t] = wal[t] + wr2[t]/sums[t/5];

  for (int i=0;i<32;++i){
    int h = w*32 + i;
    const float* row = Ws_w + (long)h*512;
    float a = 0.f;
    #pragma unroll
    for (int it=0; it<8; ++it) a += s[lane+64*it]*row[lane+64*it];
    a = wred(a);
    if (lane==0) WsS_o[b*512+h] = a;
  }
}

// =================== K2: q_t / r_t weighted sums (flat float4) =============
#define NQT4 (BB*60*128)
__global__ __launch_bounds__(256) void k_wsum(
    const float* __restrict__ h_q, const float* __restrict__ h_r,
    const float* __restrict__ wq, const float* __restrict__ cw,
    float* __restrict__ q_t, float* __restrict__ r_t)
{
  __shared__ float cf[5];
  long idx = (long)blockIdx.x*256 + threadIdx.x;
  if (blockIdx.x < 480) {
    int b = (int)(idx / (60*128));
    if (threadIdx.x < 5) cf[threadIdx.x] = wq[b*5+threadIdx.x];
    __syncthreads();
    int rem = (int)(idx % (60*128));
    int l = rem/128, h4 = rem&127;
    const float4* src = (const float4*)h_q;
    float4 acc = {0,0,0,0};
    #pragma unroll
    for (int n=0;n<5;++n){
      float4 v = src[(((long)(b*5+n)*60 + l)<<7) + h4];
      float ww = cf[n];
      acc.x += ww*v.x; acc.y += ww*v.y; acc.z += ww*v.z; acc.w += ww*v.w;
    }
    ((float4*)q_t)[((long)(b*60+l)<<7) + h4] = acc;
  } else {
    long j = idx - NQT4;
    int bk = (int)(j / (100*128));
    if (threadIdx.x < 5) cf[threadIdx.x] = cw[bk*5+threadIdx.x];
    __syncthreads();
    int rem = (int)(j % (100*128));
    int l = rem/128, h4 = rem&127;
    const float4* src = (const float4*)h_r;
    float4 acc = {0,0,0,0};
    #pragma unroll
    for (int n=0;n<5;++n){
      float4 v = src[(((long)(bk*5+n)*100 + l)<<7) + h4];
      float ww = cf[n];
      acc.x += ww*v.x; acc.y += ww*v.y; acc.z += ww*v.z; acc.w += ww*v.w;
    }
    ((float4*)r_t)[((long)(bk*100+l)<<7) + h4] = acc;
  }
}

// ============ K3: qU = q_t @ U_w^T via transposed UT (coalesced) ===========
__global__ __launch_bounds__(256) void k_qU(
    const float* __restrict__ q_t, const float* __restrict__ UT, float* __restrict__ qU)
{
  __shared__ float qt[4*512];
  int bid = blockIdx.x; int b = bid/15, tile = bid%15, q0 = tile*4, t = threadIdx.x;
  for (int i=t;i<2048;i+=256) qt[i] = q_t[(long)(b*60+q0)*512 + i];
  __syncthreads();
  float acc0[4]={}, acc1[4]={};
  for (int kk=0; kk<512; kk+=4){
    float w1[4], w2[4];
    #pragma unroll
    for (int j=0;j<4;++j){
      w1[j] = UT[(long)(kk+j)*512 + t];
      w2[j] = UT[(long)(kk+j)*512 + 256 + t];
    }
    #pragma unroll
    for (int qi=0; qi<4; ++qi){
      float4 qv = *(const float4*)&qt[qi*512+kk];
      acc0[qi] += qv.x*w1[0]+qv.y*w1[1]+qv.z*w1[2]+qv.w*w1[3];
      acc1[qi] += qv.x*w2[0]+qv.y*w2[1]+qv.z*w2[2]+qv.w*w2[3];
    }
  }
  #pragma unroll
  for (int qi=0;qi<4;++qi){
    qU[(long)(b*60+q0+qi)*512 + t]       = acc0[qi];
    qU[(long)(b*60+q0+qi)*512 + 256 + t] = acc1[qi];
  }
}

// ====== K4: U-max + alpha softmaxes — 1024 thr, 4-way K-split in block =====
__global__ __launch_bounds__(1024) void k_umax(
    const float* __restrict__ qU, const float* __restrict__ r_t,
    float* __restrict__ aq, float* __restrict__ ar)
{
  __shared__ float qb[4*60*33];    // per-group staged qU k-chunk (stride 33)
  __shared__ float rb[4*100*33];   // per-group staged r_t k-chunk
  __shared__ float C[6000];        // full pre-tanh score matrix 60x100
  __shared__ float uq[60], ur[100], scal[4];
  int bid = blockIdx.x; int b = bid>>2, k = bid&3, t = threadIdx.x;
  int g = t>>8, u = t&255;
  bool act = u < 255;
  int tq = u/17, tr = u%17;
  int q0 = tq*4, r0 = tr*6;
  int nv = (r0+6<=100)? 6 : (100-r0);
  float acc[4][6] = {};
  const float* qbase = qU + (long)b*60*512;
  const float* rbase = r_t + (long)(b*4+k)*100*512;
  float* qg = qb + g*60*33;
  float* rg = rb + g*100*33;
  for (int cc=0; cc<4; ++cc){
    int k0 = (g*4+cc)*32;
    for (int i=u; i<60*32; i+=256){ int q=i>>5, hh=i&31; qg[q*33+hh] = qbase[(long)q*512 + k0 + hh]; }
    for (int i=u; i<100*32; i+=256){ int r=i>>5, hh=i&31; rg[r*33+hh] = rbase[(long)r*512 + k0 + hh]; }
    __syncthreads();
    if (act){
      for (int hh=0; hh<32; ++hh){
        float a0=qg[(q0+0)*33+hh], a1=qg[(q0+1)*33+hh], a2=qg[(q0+2)*33+hh], a3=qg[(q0+3)*33+hh];
        #pragma unroll
        for (int j=0;j<6;++j){
          float rv = rg[(r0+j)*33+hh];
          acc[0][j]+=a0*rv; acc[1][j]+=a1*rv; acc[2][j]+=a2*rv; acc[3][j]+=a3*rv;
        }
      }
    }
    __syncthreads();
  }
  // merge partials: 4 serialized rounds (group 0 writes, 1..3 accumulate)
  for (int gi=0; gi<4; ++gi){
    if (g==gi && act){
      #pragma unroll
      for (int i=0;i<4;++i)
        for (int j=0;j<6;++j) if (j<nv){
          int cell = (q0+i)*100 + (r0+j);
          if (gi==0) C[cell] = acc[i][j];
          else       C[cell] += acc[i][j];
        }
    }
    __syncthreads();
  }
  if (t<60){
    float m=-1e30f;
    for (int i=0;i<100;++i) m = fmaxf(m, C[t*100+i]);
    uq[t] = tanhf(m);
  } else if (t>=64 && t<164){
    int rr = t-64;
    float m=-1e30f;
    for (int q=0;q<60;++q) m = fmaxf(m, C[q*100+rr]);
    ur[rr] = tanhf(m);
  }
  __syncthreads();
  if (t==0){ float M=-1e30f; for(int q=0;q<60;++q) M=fmaxf(M,uq[q]); scal[0]=M; }
  if (t==64){ float M=-1e30f; for(int r=0;r<100;++r) M=fmaxf(M,ur[r]); scal[1]=M; }
  __syncthreads();
  if (t<60) uq[t]=expf(uq[t]-scal[0]);
  if (t>=64&&t<164) ur[t-64]=expf(ur[t-64]-scal[1]);
  __syncthreads();
  if (t==0){ float S=0; for(int q=0;q<60;++q)S+=uq[q]; scal[2]=S; }
  if (t==64){ float S=0; for(int r=0;r<100;++r)S+=ur[r]; scal[3]=S; }
  __syncthreads();
  if (t<60) aq[(long)bid*60 + t] = uq[t]/scal[2];
  if (t>=64&&t<164) ar[(long)bid*100 + (t-64)] = ur[t-64]/scal[3];
}

// ====== K5: e = tanh(WsS + pai@Wqr^T + b + cov*Wc) @ Vr (WqrT coalesced) ===
__global__ __launch_bounds__(256) void k_proj_e(
    const float* __restrict__ q_t, const float* __restrict__ r_t,
    const float* __restrict__ aq, const float* __restrict__ ar,
    const float* __restrict__ q_mask, const float* __restrict__ r_mask,
    const float* __restrict__ WqrT, const float* __restrict__ Wqr_b,
    const float* __restrict__ Wc_w, const float* __restrict__ Vr_w,
    const float* __restrict__ WsS, const float* __restrict__ qr_cov,
    float* __restrict__ e_o)
{
  __shared__ float pt[16*512];
  __shared__ float cov[16], coef[16];
  __shared__ float wbuf[16*4];
  int bid = blockIdx.x;
  int b = bid / 29, tile = bid % 29;
  int l0 = tile*16, t = threadIdx.x;
  int nrows = (460-l0 < 16)? (460-l0) : 16;
  if (t<16){
    float pc=0.f, cv=0.f;
    if (t<nrows){
      int l = l0+t;
      cv = qr_cov[b*460+l];
      if (l < 60){
        float s4 = aq[(b*4+0)*60+l]+aq[(b*4+1)*60+l]+aq[(b*4+2)*60+l]+aq[(b*4+3)*60+l];
        pc = s4 * q_mask[b*60+l] * 0.25f;
      } else {
        pc = ar[b*400+(l-60)] * r_mask[b*400+(l-60)];
      }
    }
    coef[t]=pc; cov[t]=cv;
  }
  __syncthreads();
  for (int i=t;i<16*512;i+=256){
    int r = i>>9, d = i&511;
    float v = 0.f;
    if (r < nrows){
      int l = l0+r;
      v = (l<60) ? q_t[((long)(b*60+l)<<9)+d] : r_t[((long)(b*400+(l-60))<<9)+d];
      v *= coef[r];
    }
    pt[i]=v;
  }
  __syncthreads();
  float acc0[16]={}, acc1[16]={};
  for (int kk=0;kk<512;kk+=4){
    float w1[4], w2[4];
    #pragma unroll
    for (int j=0;j<4;++j){
      w1[j] = WqrT[(long)(kk+j)*512 + t];
      w2[j] = WqrT[(long)(kk+j)*512 + 256 + t];
    }
    #pragma unroll
    for (int r=0;r<16;++r){
      float4 p = *(const float4*)&pt[r*512+kk];
      acc0[r] += p.x*w1[0]+p.y*w1[1]+p.z*w1[2]+p.w*w1[3];
      acc1[r] += p.x*w2[0]+p.y*w2[1]+p.z*w2[2]+p.w*w2[3];
    }
  }
  float ws1 = WsS[b*512+t], ws2 = WsS[b*512+256+t];
  float wb1 = Wqr_b[t], wb2 = Wqr_b[256+t];
  float wc1 = Wc_w[t], wc2 = Wc_w[256+t];
  float vr1 = Vr_w[t], vr2 = Vr_w[256+t];
  int lane = t & 63, wid = t >> 6;
  #pragma unroll
  for (int r=0;r<16;++r){
    float v = tanhf(ws1 + acc0[r] + wb1 + cov[r]*wc1)*vr1
            + tanhf(ws2 + acc1[r] + wb2 + cov[r]*wc2)*vr2;
    v = wred(v);
    if (lane==0) wbuf[r*4+wid] = v;
  }
  __syncthreads();
  if (t<nrows) e_o[b*460+l0+t] = wbuf[t*4]+wbuf[t*4+1]+wbuf[t*4+2]+wbuf[t*4+3];
}

// === K6: attn softmax + c_t + p_gen + hid (grid 16, block 1024, pai fused) =
__global__ __launch_bounds__(1024) void k_attnfin(
    const float* __restrict__ e_i, const float* __restrict__ q_mask, const float* __restrict__ r_mask,
    const float* __restrict__ qr_cov,
    const float* __restrict__ q_t, const float* __restrict__ r_t,
    const float* __restrict__ aq, const float* __restrict__ ar,
    const float* __restrict__ sthat, const float* __restrict__ pg_w, const float* __restrict__ pg_b,
    const float* __restrict__ pv1_w, const float* __restrict__ pv1_b,
    float* __restrict__ a_o, float* __restrict__ hid_o, float* __restrict__ pgen_o,
    float* __restrict__ out_ct, float* __restrict__ out_a, float* __restrict__ out_cov)
{
  __shared__ float aL[460], coefL[460], hst[1024], parts[1024], red[16];
  int b = blockIdx.x, t = threadIdx.x, w = t>>6, lane = t&63;
  if (t<512) hst[t] = sthat[b*512+t];
  float ev = (t<460) ? e_i[b*460+t] : -1e30f;
  float m = wredmax(ev);
  if (lane==0) red[w]=m;
  __syncthreads();
  float M=-1e30f;
  #pragma unroll
  for (int i=0;i<16;++i) M=fmaxf(M,red[i]);
  __syncthreads();
  float x = 0.f;
  if (t<460){
    float mk = (t<60) ? q_mask[b*60+t] : r_mask[b*400+(t-60)];
    x = expf(ev-M)*mk;
  }
  float sr = wred(x);
  if (lane==0) red[w]=sr;
  __syncthreads();
  float S=0.f;
  #pragma unroll
  for (int i=0;i<16;++i) S+=red[i];
  __syncthreads();
  if (t<460){
    float v = x/S;
    aL[t]=v;
    a_o[b*460+t]=v; out_a[b*460+t]=v; out_cov[b*460+t]=qr_cov[b*460+t]+v;
    float pc;
    if (t<60){
      float s4 = aq[(b*4+0)*60+t]+aq[(b*4+1)*60+t]+aq[(b*4+2)*60+t]+aq[(b*4+3)*60+t];
      pc = s4 * q_mask[b*60+t] * 0.25f;
    } else {
      pc = ar[b*400+(t-60)] * r_mask[b*400+(t-60)];
    }
    coefL[t]=v*pc;
  }
  __syncthreads();
  {
    int h = t&511, seg = t>>9;
    float a0 = 0.f, a1 = 0.f;
    int lA = seg*230;
    #pragma unroll 4
    for (int i=0; i<230; i+=2){
      int l1 = lA+i, l2 = lA+i+1;
      const float* s1 = (l1<60) ? (q_t + ((long)(b*60+l1)<<9))
                                : (r_t + ((long)(b*400+(l1-60))<<9));
      const float* s2 = (l2<60) ? (q_t + ((long)(b*60+l2)<<9))
                                : (r_t + ((long)(b*400+(l2-60))<<9));
      a0 += coefL[l1]*s1[h];
      a1 += coefL[l2]*s2[h];
    }
    parts[t]=a0+a1;
  }
  __syncthreads();
  if (t<512){
    float ct = parts[t]+parts[512+t];
    hst[512+t]=ct;
    out_ct[b*512+t]=ct;
  }
  __syncthreads();
  {
    float p = hst[t]*pg_w[t];
    p = wred(p);
    if (lane==0) red[w]=p;
  }
  __syncthreads();
  if (t==0){
    float pp = pg_b[0];
    #pragma unroll
    for (int i=0;i<16;++i) pp+=red[i];
    pgen_o[b]=sigm(pp);
  }
  for (int i=0;i<32;++i){
    int h = w*32+i;
    const float* row = pv1_w + (long)h*1024;
    float a = 0.f;
    #pragma unroll
    for (int it=0; it<16; ++it) a += hst[lane+64*it]*row[lane+64*it];
    a = wred(a);
    if (lane==0) hid_o[b*512+h] = a + pv1_b[h];
  }
}

// ================== K7: vocab logits (4 threads per row) ===================
__global__ __launch_bounds__(256) void k_logits(
    const float* __restrict__ hid, const float* __restrict__ pv2_w, const float* __restrict__ pv2_b,
    float* __restrict__ logits)
{
  __shared__ float hs[16*512];
  int t = threadIdx.x;
  for (int i=t;i<8192;i+=256) hs[i]=hid[i];
  __syncthreads();
  int vl = t>>2, seg = t&3;
  long v = (long)blockIdx.x*64 + vl;
  float acc[16]={};
  if (v < VOCABN){
    const float4* wr = (const float4*)(pv2_w + v*512 + seg*128);
    const float4* hv = ((const float4*)hs) + seg*32;
    for (int i=0;i<32;++i){
      int j = (i + seg*2)&31;
      float4 wv = wr[j];
      #pragma unroll
      for (int b2=0;b2<16;++b2){
        float4 h = hv[b2*128+j];
        acc[b2] += wv.x*h.x+wv.y*h.y+wv.z*h.z+wv.w*h.w;
      }
    }
  }
  #pragma unroll
  for (int b2=0;b2<16;++b2){
    acc[b2] += __shfl_xor(acc[b2],1);
    acc[b2] += __shfl_xor(acc[b2],2);
  }
  if (seg==0 && v < VOCABN){
    float bias = pv2_b[v];
    #pragma unroll
    for (int b2=0;b2<16;++b2) logits[(long)b2*VOCABN+v] = acc[b2]+bias;
  }
}

// ============ K8: vocab softmax + final dist + scatter-add =================
__global__ __launch_bounds__(1024) void k_final(
    const float* __restrict__ logits, const float* __restrict__ extra_zeros,
    const float* __restrict__ a_ws, const float* __restrict__ pgen,
    const int* __restrict__ bev, float* __restrict__ out)
{
  __shared__ float red[16];
  int b = blockIdx.x, t = threadIdx.x, w=t>>6, lane=t&63;
  const float* lg = logits + (long)b*VOCABN;
  float lm=-1e30f;
  for (int v=t; v<VOCABN; v+=1024) lm=fmaxf(lm, lg[v]);
  lm = wredmax(lm);
  if (lane==0) red[w]=lm;
  __syncthreads();
  float M=-1e30f;
  #pragma unroll
  for (int i=0;i<16;++i) M=fmaxf(M,red[i]);
  __syncthreads();
  float ls=0;
  for (int v=t;v<VOCABN;v+=1024) ls += expf(lg[v]-M);
  ls = wred(ls);
  if (lane==0) red[w]=ls;
  __syncthreads();
  float S=0;
  #pragma unroll
  for (int i=0;i<16;++i) S+=red[i];
  float pg = pgen[b];
  float sc = pg/S;
  float* ob = out + (long)b*(VOCABN+EXTRAN);
  for (int v=t;v<VOCABN;v+=1024) ob[v] = expf(lg[v]-M)*sc;
  if (t<EXTRAN) ob[VOCABN+t] = extra_zeros[b*EXTRAN+t];
  __syncthreads();
  float opg = 1.0f-pg;
  for (int l=t;l<460;l+=1024){
    atomicAdd(&ob[bev[b*460+l]], opg*a_ws[b*460+l]);
  }
}

extern "C" void kernel_launch(void* const* d_in, const int* in_sizes, int n_in,
                              void* d_out, int out_size, void* d_ws, size_t ws_size,
                              hipStream_t stream)
{
  (void)in_sizes; (void)n_in; (void)out_size; (void)ws_size;
  const float* y_t   = (const float*)d_in[0];
  const float* h0    = (const float*)d_in[1];
  const float* c0    = (const float*)d_in[2];
  const float* c_t_0 = (const float*)d_in[3];
  const float* o_m   = (const float*)d_in[4];
  const float* h_q   = (const float*)d_in[5];
  const float* q_mask= (const float*)d_in[6];
  const float* q_a   = (const float*)d_in[7];
  const float* h_r   = (const float*)d_in[8];
  const float* r_mask= (const float*)d_in[9];
  const float* r_a   = (const float*)d_in[10];
  const float* r_o   = (const float*)d_in[11];
  const float* qr_cov= (const float*)d_in[12];
  const float* extra_zeros=(const float*)d_in[13];
  const float* xc_w  = (const float*)d_in[14];
  const float* xc_b  = (const float*)d_in[15];
  const float* w_ih  = (const float*)d_in[16];
  const float* w_hh  = (const float*)d_in[17];
  const float* b_ih  = (const float*)d_in[18];
  const float* b_hh  = (const float*)d_in[19];
  const float* dsq_w = (const float*)d_in[20];
  const float* dsa_w = (const float*)d_in[21];
  const float* dso_w = (const float*)d_in[22];
  const float* U_w   = (const float*)d_in[23];
  const float* Wc_w  = (const float*)d_in[24];
  const float* Ws_w  = (const float*)d_in[25];
  const float* Wqr_w = (const float*)d_in[26];
  const float* Wqr_b = (const float*)d_in[27];
  const float* Vr_w  = (const float*)d_in[28];
  const float* pg_w  = (const float*)d_in[29];
  const float* pg_b  = (const float*)d_in[30];
  const float* pv1_w = (const float*)d_in[31];
  const float* pv1_b = (const float*)d_in[32];
  const float* pv2_w = (const float*)d_in[33];
  const float* pv2_b = (const float*)d_in[34];
  const int*   bev   = (const int*)d_in[35];

  float* out = (float*)d_out;
  float* out_fd  = out;
  float* out_h1  = out_fd + (size_t)16*(VOCABN+EXTRAN);
  float* out_c1  = out_h1 + 16*256;
  float* out_ct  = out_c1 + 16*256;
  float* out_a   = out_ct + 16*512;
  float* out_cov = out_a  + 16*460;

  float* ws = (float*)d_ws;
  size_t o = 0;
  float* sthat = ws + o; o += 16*512;
  float* wq    = ws + o; o += 16*8;
  float* cw    = ws + o; o += 16*32;
  float* WsS   = ws + o; o += 16*512;
  float* UT    = ws + o; o += (size_t)512*512;
  float* WqrT  = ws + o; o += (size_t)512*512;
  float* q_t   = ws + o; o += (size_t)16*60*512;
  float* r_t   = ws + o; o += (size_t)16*400*512;
  float* qU    = ws + o; o += (size_t)16*60*512;
  float* aq    = ws + o; o += 16*4*64;
  float* ar    = ws + o; o += 16*4*112;
  float* e_b   = ws + o; o += 16*512;
  float* a_b   = ws + o; o += 16*512;
  float* hid_b = ws + o; o += 16*512;
  float* pgen  = ws + o; o += 64;
  float* logits= ws + o; o += (size_t)16*VOCABN;

  hipLaunchKernelGGL(k_tr, dim3(512), dim3(256), 0, stream, U_w, Wqr_w, UT, WqrT);
  hipLaunchKernelGGL(k_head, dim3(16), dim3(1024), 0, stream,
      y_t,h0,c0,c_t_0,o_m,q_a,r_a,r_o,
      xc_w,xc_b,w_ih,w_hh,b_ih,b_hh,dsq_w,dsa_w,dso_w,Ws_w,
      sthat,out_h1,out_c1, wq,cw,WsS);
  hipLaunchKernelGGL(k_wsum, dim3(3680), dim3(256), 0, stream,
      h_q,h_r,wq,cw, q_t,r_t);
  hipLaunchKernelGGL(k_qU, dim3(240), dim3(256), 0, stream, q_t, UT, qU);
  hipLaunchKernelGGL(k_umax, dim3(64), dim3(1024), 0, stream, qU, r_t, aq, ar);
  hipLaunchKernelGGL(k_proj_e, dim3(464), dim3(256), 0, stream,
      q_t,r_t,aq,ar,q_mask,r_mask,WqrT,Wqr_b,Wc_w,Vr_w,WsS,qr_cov, e_b);
  hipLaunchKernelGGL(k_attnfin, dim3(16), dim3(1024), 0, stream,
      e_b,q_mask,r_mask,qr_cov,q_t,r_t,aq,ar,sthat,pg_w,pg_b,pv1_w,pv1_b,
      a_b,hid_b,pgen, out_ct,out_a,out_cov);
  hipLaunchKernelGGL(k_logits, dim3((VOCABN+63)/64), dim3(256), 0, stream,
      hid_b, pv2_w, pv2_b, logits);
  hipLaunchKernelGGL(k_final, dim3(16), dim3(1024), 0, stream,
      logits, extra_zeros, a_b, pgen, bev, out_fd);
}

// Round 4
// 684.073 us; speedup vs baseline: 1.5750x; 1.1340x over previous
//
#include <hip/hip_runtime.h>
#include <math.h>

#define BB 16
#define H2N 512
#define VOCABN 50000
#define EXTRAN 100
#define LTOT 460
#define EPSF 1e-12f

__device__ __forceinline__ float sigm(float x){ return 1.0f/(1.0f+expf(-x)); }

__device__ __forceinline__ float wred(float v){
  #pragma unroll
  for (int s=32;s>0;s>>=1) v += __shfl_xor(v,s);
  return v;
}
__device__ __forceinline__ float wredmax(float v){
  #pragma unroll
  for (int s=32;s>0;s>>=1) v = fmaxf(v, __shfl_xor(v,s));
  return v;
}

// ======= K0: repack U_w, Wqr_w into [k4][col][4] layout (coalesced GEMM) ===
__global__ __launch_bounds__(256) void k_w4(
    const float* __restrict__ A, const float* __restrict__ B,
    float* __restrict__ A4, float* __restrict__ B4)
{
  int idx = blockIdx.x*256 + threadIdx.x;     // 2 * 65536 float4 slots
  int m = idx >> 16;
  int r = idx & 65535;
  int k4 = r >> 9;          // 0..127
  int h  = r & 511;         // 0..511
  const float* src = m ? B : A;
  float* dst = m ? B4 : A4;
  float4 v = *(const float4*)(src + (long)h*512 + k4*4);
  *(float4*)(dst + (long)k4*2048 + h*4) = v;   // consecutive h -> coalesced write
}

// ======================= K1: fused LSTM + dynamic-select head ==============
__global__ __launch_bounds__(1024) void k_head(
    const float* __restrict__ y_t, const float* __restrict__ h0, const float* __restrict__ c0,
    const float* __restrict__ c_t_0, const float* __restrict__ o_m,
    const float* __restrict__ q_a, const float* __restrict__ r_a, const float* __restrict__ r_o,
    const float* __restrict__ xc_w, const float* __restrict__ xc_b,
    const float* __restrict__ w_ih, const float* __restrict__ w_hh,
    const float* __restrict__ b_ih, const float* __restrict__ b_hh,
    const float* __restrict__ dsq_w, const float* __restrict__ dsa_w, const float* __restrict__ dso_w,
    const float* __restrict__ Ws_w,
    float* __restrict__ sthat, float* __restrict__ out_h1, float* __restrict__ out_c1,
    float* __restrict__ wq_o, float* __restrict__ cw_o, float* __restrict__ WsS_o)
{
  __shared__ float cat[640], h0s[256], xls[128], gs[1024];
  __shared__ float s[512], om[640], qa_l[640];
  __shared__ float part[1024];
  __shared__ float tq[128], ta[128], to2[128];
  __shared__ float wr2[20], wal[20], sums[4], wql[8], scal[4];
  int b = blockIdx.x, t = threadIdx.x;
  int w = t>>6, lane = t&63;

  if (t < 640){
    cat[t] = (t<128) ? y_t[b*128+t] : c_t_0[b*512 + (t-128)];
    om[t]  = o_m[b*640+t];
    qa_l[t]= q_a[b*640+t];
  } else if (t < 896){
    h0s[t-640] = h0[b*256 + (t-640)];
  }
  __syncthreads();

  {
    int j0 = w*8;
    for (int i=0;i<8;++i){
      int j = j0+i;
      const float* row = xc_w + j*640;
      float a = 0.f;
      #pragma unroll
      for (int it=0; it<10; ++it) a += cat[lane+64*it]*row[lane+64*it];
      a = wred(a);
      if (lane==0) xls[j] = a + xc_b[j];
    }
  }
  __syncthreads();

  {
    int r0 = w*64;
    for (int i=0;i<64;++i){
      int r = r0+i;
      const float* wi = w_ih + r*128;
      const float* wh = w_hh + r*256;
      float a = xls[lane]*wi[lane] + xls[lane+64]*wi[lane+64];
      #pragma unroll
      for (int it=0; it<4; ++it) a += h0s[lane+64*it]*wh[lane+64*it];
      a = wred(a);
      if (lane==0) gs[r] = a + b_ih[r] + b_hh[r];
    }
  }
  __syncthreads();

  if (t < 256){
    float c1v = sigm(gs[256+t])*c0[b*256+t] + sigm(gs[t])*tanhf(gs[512+t]);
    float h1v = sigm(gs[768+t])*tanhf(c1v);
    s[t] = h1v; s[256+t] = c1v;
    sthat[b*512+t] = h1v; sthat[b*512+256+t] = c1v;
    out_h1[b*256+t] = h1v; out_c1[b*256+t] = c1v;
  }
  __syncthreads();

  {
    int j = t&127, seg = t>>7, d0 = seg*64;
    float a = 0.f;
    #pragma unroll 8
    for (int it=0; it<64; ++it){ int d = d0+it; a += s[d]*dsq_w[d*128+j]; }
    part[seg*128+j] = a;
  }
  __syncthreads();
  if (t < 128){
    float a = 0.f;
    #pragma unroll
    for (int sg=0; sg<8; ++sg) a += part[sg*128+t];
    tq[t] = a;
  }
  __syncthreads();

  if (w < 5){
    float p = tq[lane]*qa_l[w*128+lane] + tq[lane+64]*qa_l[w*128+64+lane];
    p = wred(p);
    if (lane==0) wr2[w] = tanhf(p);
  }
  __syncthreads();
  if (t==0){ float sm=EPSF; for(int n=0;n<5;++n) sm+=wr2[n]; scal[0]=sm; }
  __syncthreads();
  if (t<5){ float v = wr2[t]/scal[0]; wql[t]=v; wq_o[b*5+t]=v; }
  __syncthreads();
  if (t<128){
    float a=0.f;
    #pragma unroll
    for (int n=0;n<5;++n) a += wql[n]*qa_l[n*128+t];
    tq[t]=a;
  }
  __syncthreads();

  {
    int j = t&127, seg = t>>7, d0 = seg*80;
    float a = 0.f;
    for (int it=0; it<80; ++it){
      int d = d0+it;
      float sv = (d<512) ? s[d] : tq[d-512];
      a += sv*dsa_w[d*128+j];
    }
    part[seg*128+j] = a;
  }
  __syncthreads();
  if (t < 128){
    float a=0.f;
    #pragma unroll
    for (int sg=0; sg<8; ++sg) a += part[sg*128+t];
    ta[t]=a;
  }
  __syncthreads();

  for (int oo=w; oo<20; oo+=16){
    const float* ra = r_a + ((long)(b*4 + oo/5)*5 + (oo%5))*128;
    float p = ta[lane]*ra[lane] + ta[lane+64]*ra[lane+64];
    p = wred(p);
    if (lane==0) wr2[oo] = tanhf(p);
  }
  __syncthreads();
  if (t<4){ float sm=EPSF; for(int n=0;n<5;++n) sm+=wr2[t*5+n]; sums[t]=sm; }
  __syncthreads();
  if (t<20) wal[t] = wr2[t]/sums[t/5];
  __syncthreads();

  {
    int j = t&127, seg = t>>7, d0 = seg*144;
    float a = 0.f;
    for (int it=0; it<144; ++it){
      int d = d0+it;
      float sv = (d<512) ? s[d] : om[d-512];
      a += sv*dso_w[d*128+j];
    }
    part[seg*128+j] = a;
  }
  __syncthreads();
  if (t < 128){
    float a=0.f;
    #pragma unroll
    for (int sg=0; sg<8; ++sg) a += part[sg*128+t];
    to2[t]=a;
  }
  __syncthreads();

  for (int oo=w; oo<20; oo+=16){
    const float* ro = r_o + ((long)(b*4 + oo/5)*5 + (oo%5))*128;
    float p = to2[lane]*ro[lane] + to2[lane+64]*ro[lane+64];
    p = wred(p);
    if (lane==0) wr2[oo] = tanhf(p);
  }
  __syncthreads();
  if (t<4){ float sm=EPSF; for(int n=0;n<5;++n) sm+=wr2[t*5+n]; sums[t]=sm; }
  __syncthreads();
  if (t<20) cw_o[b*20+t] = wal[t] + wr2[t]/sums[t/5];

  for (int i=0;i<32;++i){
    int h = w*32 + i;
    const float* row = Ws_w + (long)h*512;
    float a = 0.f;
    #pragma unroll
    for (int it=0; it<8; ++it) a += s[lane+64*it]*row[lane+64*it];
    a = wred(a);
    if (lane==0) WsS_o[b*512+h] = a;
  }
}

// =================== K2: q_t / r_t weighted sums (flat float4) =============
#define NQT4 (BB*60*128)
__global__ __launch_bounds__(256) void k_wsum(
    const float* __restrict__ h_q, const float* __restrict__ h_r,
    const float* __restrict__ wq, const float* __restrict__ cw,
    float* __restrict__ q_t, float* __restrict__ r_t)
{
  __shared__ float cf[5];
  long idx = (long)blockIdx.x*256 + threadIdx.x;
  if (blockIdx.x < 480) {
    int b = (int)(idx / (60*128));
    if (threadIdx.x < 5) cf[threadIdx.x] = wq[b*5+threadIdx.x];
    __syncthreads();
    int rem = (int)(idx % (60*128));
    int l = rem/128, h4 = rem&127;
    const float4* src = (const float4*)h_q;
    float4 acc = {0,0,0,0};
    #pragma unroll
    for (int n=0;n<5;++n){
      float4 v = src[(((long)(b*5+n)*60 + l)<<7) + h4];
      float ww = cf[n];
      acc.x += ww*v.x; acc.y += ww*v.y; acc.z += ww*v.z; acc.w += ww*v.w;
    }
    ((float4*)q_t)[((long)(b*60+l)<<7) + h4] = acc;
  } else {
    long j = idx - NQT4;
    int bk = (int)(j / (100*128));
    if (threadIdx.x < 5) cf[threadIdx.x] = cw[bk*5+threadIdx.x];
    __syncthreads();
    int rem = (int)(j % (100*128));
    int l = rem/128, h4 = rem&127;
    const float4* src = (const float4*)h_r;
    float4 acc = {0,0,0,0};
    #pragma unroll
    for (int n=0;n<5;++n){
      float4 v = src[(((long)(bk*5+n)*100 + l)<<7) + h4];
      float ww = cf[n];
      acc.x += ww*v.x; acc.y += ww*v.y; acc.z += ww*v.z; acc.w += ww*v.w;
    }
    ((float4*)r_t)[((long)(bk*100+l)<<7) + h4] = acc;
  }
}

// ======== K3: qU = q_t @ U^T — col-split, U4 layout, reg-tiled =============
__global__ __launch_bounds__(256) void k_qU(
    const float* __restrict__ q_t, const float* __restrict__ U4, float* __restrict__ qU)
{
  __shared__ float qt[4*512];
  int bid = blockIdx.x;                 // 16 b * 15 tiles * 2 halves = 480
  int b = bid / 30; int r2 = bid % 30; int tile = r2 >> 1; int half = r2 & 1;
  int q0 = tile*4; int C0 = half*256;
  int t = threadIdx.x;
  {
    const float4* src = (const float4*)(q_t + (long)(b*60+q0)*512);
    ((float4*)qt)[t]     = src[t];
    ((float4*)qt)[t+256] = src[t+256];
  }
  __syncthreads();
  int c0 = t&63, rg = t>>6;             // rg = row 0..3
  float acc[4] = {};
  #pragma unroll 2
  for (int k4=0; k4<128; ++k4){
    float4 p = *(const float4*)&qt[rg*512 + k4*4];
    #pragma unroll
    for (int m=0;m<4;++m){
      float4 wv = *(const float4*)(U4 + (long)k4*2048 + (C0 + c0 + 64*m)*4);
      acc[m] += p.x*wv.x + p.y*wv.y + p.z*wv.z + p.w*wv.w;
    }
  }
  #pragma unroll
  for (int m=0;m<4;++m)
    qU[(long)(b*60+q0+rg)*512 + C0 + c0 + 64*m] = acc[m];
}

// ====== K4: U-max + alpha softmaxes — 1024 thr, 4-way K-split in block =====
__global__ __launch_bounds__(1024) void k_umax(
    const float* __restrict__ qU, const float* __restrict__ r_t,
    float* __restrict__ aq, float* __restrict__ ar)
{
  __shared__ float qb[4*60*33];
  __shared__ float rb[4*100*33];
  __shared__ float C[6000];
  __shared__ float uq[60], ur[100], scal[4];
  int bid = blockIdx.x; int b = bid>>2, k = bid&3, t = threadIdx.x;
  int g = t>>8, u = t&255;
  bool act = u < 255;
  int tq = u/17, tr = u%17;
  int q0 = tq*4, r0 = tr*6;
  int nv = (r0+6<=100)? 6 : (100-r0);
  float acc[4][6] = {};
  const float* qbase = qU + (long)b*60*512;
  const float* rbase = r_t + (long)(b*4+k)*100*512;
  float* qg = qb + g*60*33;
  float* rg = rb + g*100*33;
  for (int cc=0; cc<4; ++cc){
    int k0 = (g*4+cc)*32;
    for (int i=u; i<60*32; i+=256){ int q=i>>5, hh=i&31; qg[q*33+hh] = qbase[(long)q*512 + k0 + hh]; }
    for (int i=u; i<100*32; i+=256){ int r=i>>5, hh=i&31; rg[r*33+hh] = rbase[(long)r*512 + k0 + hh]; }
    __syncthreads();
    if (act){
      for (int hh=0; hh<32; ++hh){
        float a0=qg[(q0+0)*33+hh], a1=qg[(q0+1)*33+hh], a2=qg[(q0+2)*33+hh], a3=qg[(q0+3)*33+hh];
        #pragma unroll
        for (int j=0;j<6;++j){
          float rv = rg[(r0+j)*33+hh];
          acc[0][j]+=a0*rv; acc[1][j]+=a1*rv; acc[2][j]+=a2*rv; acc[3][j]+=a3*rv;
        }
      }
    }
    __syncthreads();
  }
  for (int gi=0; gi<4; ++gi){
    if (g==gi && act){
      #pragma unroll
      for (int i=0;i<4;++i)
        for (int j=0;j<6;++j) if (j<nv){
          int cell = (q0+i)*100 + (r0+j);
          if (gi==0) C[cell] = acc[i][j];
          else       C[cell] += acc[i][j];
        }
    }
    __syncthreads();
  }
  if (t<60){
    float m=-1e30f;
    for (int i=0;i<100;++i) m = fmaxf(m, C[t*100+i]);
    uq[t] = tanhf(m);
  } else if (t>=64 && t<164){
    int rr = t-64;
    float m=-1e30f;
    for (int q=0;q<60;++q) m = fmaxf(m, C[q*100+rr]);
    ur[rr] = tanhf(m);
  }
  __syncthreads();
  if (t==0){ float M=-1e30f; for(int q=0;q<60;++q) M=fmaxf(M,uq[q]); scal[0]=M; }
  if (t==64){ float M=-1e30f; for(int r=0;r<100;++r) M=fmaxf(M,ur[r]); scal[1]=M; }
  __syncthreads();
  if (t<60) uq[t]=expf(uq[t]-scal[0]);
  if (t>=64&&t<164) ur[t-64]=expf(ur[t-64]-scal[1]);
  __syncthreads();
  if (t==0){ float S=0; for(int q=0;q<60;++q)S+=uq[q]; scal[2]=S; }
  if (t==64){ float S=0; for(int r=0;r<100;++r)S+=ur[r]; scal[3]=S; }
  __syncthreads();
  if (t<60) aq[(long)bid*60 + t] = uq[t]/scal[2];
  if (t>=64&&t<164) ar[(long)bid*100 + (t-64)] = ur[t-64]/scal[3];
}

// ====== K5: e += Σ_half tanh(WsS + pai@Wqr^T + b + cov*Wc)·Vr  =============
// col-split (2 halves), W4 layout, 4 rows x 4 cols per thread, atomicAdd e.
__global__ __launch_bounds__(256) void k_proj_e(
    const float* __restrict__ q_t, const float* __restrict__ r_t,
    const float* __restrict__ aq, const float* __restrict__ ar,
    const float* __restrict__ q_mask, const float* __restrict__ r_mask,
    const float* __restrict__ W4, const float* __restrict__ Wqr_b,
    const float* __restrict__ Wc_w, const float* __restrict__ Vr_w,
    const float* __restrict__ WsS, const float* __restrict__ qr_cov,
    float* __restrict__ e_o)
{
  __shared__ float pt[16*512];
  __shared__ float cov[16], coef[16];
  int bid = blockIdx.x;                 // 16 b * 29 tiles * 2 halves = 928
  int b = bid / 58; int r2 = bid % 58; int tile = r2 >> 1; int half = r2 & 1;
  int l0 = tile*16; int C0 = half*256;
  int t = threadIdx.x;
  int nrows = (460-l0 < 16)? (460-l0) : 16;
  if (t<16){
    float pc=0.f, cv=0.f;
    if (t<nrows){
      int l = l0+t;
      cv = qr_cov[b*460+l];
      if (l < 60){
        float s4 = aq[(b*4+0)*60+l]+aq[(b*4+1)*60+l]+aq[(b*4+2)*60+l]+aq[(b*4+3)*60+l];
        pc = s4 * q_mask[b*60+l] * 0.25f;
      } else {
        pc = ar[b*400+(l-60)] * r_mask[b*400+(l-60)];
      }
    }
    coef[t]=pc; cov[t]=cv;
  }
  __syncthreads();
  for (int i=t;i<2048;i+=256){
    int r = i>>7, d4 = i&127;
    float4 v = {0,0,0,0};
    if (r < nrows){
      int l = l0+r;
      v = (l<60) ? ((const float4*)q_t)[((long)(b*60+l)<<7)+d4]
                 : ((const float4*)r_t)[((long)(b*400+(l-60))<<7)+d4];
      float cf = coef[r];
      v.x*=cf; v.y*=cf; v.z*=cf; v.w*=cf;
    }
    ((float4*)pt)[i] = v;
  }
  __syncthreads();
  int c0 = t&63, rg = t>>6, r0 = rg*4;
  float acc[4][4] = {};
  #pragma unroll 2
  for (int k4=0; k4<128; ++k4){
    float4 wv[4];
    #pragma unroll
    for (int m=0;m<4;++m)
      wv[m] = *(const float4*)(W4 + (long)k4*2048 + (C0 + c0 + 64*m)*4);
    #pragma unroll
    for (int r=0;r<4;++r){
      float4 p = *(const float4*)&pt[(r0+r)*512 + k4*4];
      #pragma unroll
      for (int m=0;m<4;++m)
        acc[r][m] += p.x*wv[m].x + p.y*wv[m].y + p.z*wv[m].z + p.w*wv[m].w;
    }
  }
  float wsm[4], wbm[4], wcm[4], vrm[4];
  #pragma unroll
  for (int m=0;m<4;++m){
    int h = C0 + c0 + 64*m;
    wsm[m] = WsS[b*512+h]; wbm[m] = Wqr_b[h];
    wcm[m] = Wc_w[h];      vrm[m] = Vr_w[h];
  }
  int lane = t&63;
  #pragma unroll
  for (int r=0;r<4;++r){
    int row = r0+r;
    float cv = cov[row];
    float s = 0.f;
    #pragma unroll
    for (int m=0;m<4;++m)
      s += tanhf(wsm[m] + acc[r][m] + wbm[m] + cv*wcm[m]) * vrm[m];
    s = wred(s);
    if (lane==0 && row<nrows) atomicAdd(&e_o[b*460+l0+row], s);
  }
}

// === K6: attn softmax + c_t + p_gen + hid (grid 16, block 1024) ============
__global__ __launch_bounds__(1024) void k_attnfin(
    const float* __restrict__ e_i, const float* __restrict__ q_mask, const float* __restrict__ r_mask,
    const float* __restrict__ qr_cov,
    const float* __restrict__ q_t, const float* __restrict__ r_t,
    const float* __restrict__ aq, const float* __restrict__ ar,
    const float* __restrict__ sthat, const float* __restrict__ pg_w, const float* __restrict__ pg_b,
    const float* __restrict__ pv1_w, const float* __restrict__ pv1_b,
    float* __restrict__ a_o, float* __restrict__ hid_o, float* __restrict__ pgen_o,
    float* __restrict__ out_ct, float* __restrict__ out_a, float* __restrict__ out_cov)
{
  __shared__ float aL[460], coefL[460], hst[1024], parts[1024], red[16];
  int b = blockIdx.x, t = threadIdx.x, w = t>>6, lane = t&63;
  if (t<512) hst[t] = sthat[b*512+t];
  float ev = (t<460) ? e_i[b*460+t] : -1e30f;
  float m = wredmax(ev);
  if (lane==0) red[w]=m;
  __syncthreads();
  float M=-1e30f;
  #pragma unroll
  for (int i=0;i<16;++i) M=fmaxf(M,red[i]);
  __syncthreads();
  float x = 0.f;
  if (t<460){
    float mk = (t<60) ? q_mask[b*60+t] : r_mask[b*400+(t-60)];
    x = expf(ev-M)*mk;
  }
  float sr = wred(x);
  if (lane==0) red[w]=sr;
  __syncthreads();
  float S=0.f;
  #pragma unroll
  for (int i=0;i<16;++i) S+=red[i];
  __syncthreads();
  if (t<460){
    float v = x/S;
    aL[t]=v;
    a_o[b*460+t]=v; out_a[b*460+t]=v; out_cov[b*460+t]=qr_cov[b*460+t]+v;
    float pc;
    if (t<60){
      float s4 = aq[(b*4+0)*60+t]+aq[(b*4+1)*60+t]+aq[(b*4+2)*60+t]+aq[(b*4+3)*60+t];
      pc = s4 * q_mask[b*60+t] * 0.25f;
    } else {
      pc = ar[b*400+(t-60)] * r_mask[b*400+(t-60)];
    }
    coefL[t]=v*pc;
  }
  __syncthreads();
  {
    int h = t&511, seg = t>>9;
    float a0 = 0.f, a1 = 0.f;
    int lA = seg*230;
    #pragma unroll 4
    for (int i=0; i<230; i+=2){
      int l1 = lA+i, l2 = lA+i+1;
      const float* s1 = (l1<60) ? (q_t + ((long)(b*60+l1)<<9))
                                : (r_t + ((long)(b*400+(l1-60))<<9));
      const float* s2 = (l2<60) ? (q_t + ((long)(b*60+l2)<<9))
                                : (r_t + ((long)(b*400+(l2-60))<<9));
      a0 += coefL[l1]*s1[h];
      a1 += coefL[l2]*s2[h];
    }
    parts[t]=a0+a1;
  }
  __syncthreads();
  if (t<512){
    float ct = parts[t]+parts[512+t];
    hst[512+t]=ct;
    out_ct[b*512+t]=ct;
  }
  __syncthreads();
  {
    float p = hst[t]*pg_w[t];
    p = wred(p);
    if (lane==0) red[w]=p;
  }
  __syncthreads();
  if (t==0){
    float pp = pg_b[0];
    #pragma unroll
    for (int i=0;i<16;++i) pp+=red[i];
    pgen_o[b]=sigm(pp);
  }
  for (int i=0;i<32;++i){
    int h = w*32+i;
    const float* row = pv1_w + (long)h*1024;
    float a = 0.f;
    #pragma unroll
    for (int it=0; it<16; ++it) a += hst[lane+64*it]*row[lane+64*it];
    a = wred(a);
    if (lane==0) hid_o[b*512+h] = a + pv1_b[h];
  }
}

// ====== K7: vocab exp-logits + per-batch expsum partials ===================
__global__ __launch_bounds__(256) void k_logits(
    const float* __restrict__ hid, const float* __restrict__ pv2_w, const float* __restrict__ pv2_b,
    float* __restrict__ logits, float* __restrict__ S)
{
  __shared__ float hs[16*512];
  __shared__ float ssum[16];
  int t = threadIdx.x;
  for (int i=t;i<8192;i+=256) hs[i]=hid[i];
  if (t<16) ssum[t]=0.f;
  __syncthreads();
  int vl = t>>2, seg = t&3;
  long v = (long)blockIdx.x*64 + vl;
  float acc[16]={};
  if (v < VOCABN){
    const float4* wr = (const float4*)(pv2_w + v*512 + seg*128);
    const float4* hv = ((const float4*)hs) + seg*32;
    for (int i=0;i<32;++i){
      int j = (i + seg*2)&31;
      float4 wv = wr[j];
      #pragma unroll
      for (int b2=0;b2<16;++b2){
        float4 h = hv[b2*128+j];
        acc[b2] += wv.x*h.x+wv.y*h.y+wv.z*h.z+wv.w*h.w;
      }
    }
  }
  #pragma unroll
  for (int b2=0;b2<16;++b2){
    acc[b2] += __shfl_xor(acc[b2],1);
    acc[b2] += __shfl_xor(acc[b2],2);
  }
  float bias = (v < VOCABN) ? pv2_b[v] : 0.f;
  int lane = t&63;
  #pragma unroll
  for (int b2=0;b2<16;++b2){
    float el = (v < VOCABN) ? expf(acc[b2]+bias) : 0.f;
    if (seg==0 && v < VOCABN) logits[(long)b2*VOCABN+v] = el;
    float c = (seg==0) ? el : 0.f;
    c = wred(c);
    if (lane==0) atomicAdd(&ssum[b2], c);
  }
  __syncthreads();
  if (t<16) atomicAdd(&S[t], ssum[t]);
}

// ====== K8: scale pass — out = pg*exp/S  (+extra zeros region) =============
__global__ __launch_bounds__(256) void k_scale(
    const float* __restrict__ logits, const float* __restrict__ extra_zeros,
    const float* __restrict__ pgen, const float* __restrict__ S,
    float* __restrict__ out)
{
  long idx = (long)blockIdx.x*256 + threadIdx.x;
  if (idx >= (long)BB*(VOCABN+EXTRAN)) return;
  int b = (int)(idx / (VOCABN+EXTRAN));
  int j = (int)(idx % (VOCABN+EXTRAN));
  if (j < VOCABN){
    out[idx] = logits[(long)b*VOCABN+j] * (pgen[b]/S[b]);
  } else {
    out[idx] = extra_zeros[b*EXTRAN + (j-VOCABN)];
  }
}

// ====== K9: scatter-add attn dist into extended vocab ======================
__global__ __launch_bounds__(512) void k_scatter(
    const float* __restrict__ a_ws, const float* __restrict__ pgen,
    const int* __restrict__ bev, float* __restrict__ out)
{
  int b = blockIdx.x, t = threadIdx.x;
  if (t < LTOT){
    float opg = 1.0f - pgen[b];
    atomicAdd(&out[(long)b*(VOCABN+EXTRAN) + bev[b*460+t]], opg*a_ws[b*460+t]);
  }
}

extern "C" void kernel_launch(void* const* d_in, const int* in_sizes, int n_in,
                              void* d_out, int out_size, void* d_ws, size_t ws_size,
                              hipStream_t stream)
{
  (void)in_sizes; (void)n_in; (void)out_size; (void)ws_size;
  const float* y_t   = (const float*)d_in[0];
  const float* h0    = (const float*)d_in[1];
  const float* c0    = (const float*)d_in[2];
  const float* c_t_0 = (const float*)d_in[3];
  const float* o_m   = (const float*)d_in[4];
  const float* h_q   = (const float*)d_in[5];
  const float* q_mask= (const float*)d_in[6];
  const float* q_a   = (const float*)d_in[7];
  const float* h_r   = (const float*)d_in[8];
  const float* r_mask= (const float*)d_in[9];
  const float* r_a   = (const float*)d_in[10];
  const float* r_o   = (const float*)d_in[11];
  const float* qr_cov= (const float*)d_in[12];
  const float* extra_zeros=(const float*)d_in[13];
  const float* xc_w  = (const float*)d_in[14];
  const float* xc_b  = (const float*)d_in[15];
  const float* w_ih  = (const float*)d_in[16];
  const float* w_hh  = (const float*)d_in[17];
  const float* b_ih  = (const float*)d_in[18];
  const float* b_hh  = (const float*)d_in[19];
  const float* dsq_w = (const float*)d_in[20];
  const float* dsa_w = (const float*)d_in[21];
  const float* dso_w = (const float*)d_in[22];
  const float* U_w   = (const float*)d_in[23];
  const float* Wc_w  = (const float*)d_in[24];
  const float* Ws_w  = (const float*)d_in[25];
  const float* Wqr_w = (const float*)d_in[26];
  const float* Wqr_b = (const float*)d_in[27];
  const float* Vr_w  = (const float*)d_in[28];
  const float* pg_w  = (const float*)d_in[29];
  const float* pg_b  = (const float*)d_in[30];
  const float* pv1_w = (const float*)d_in[31];
  const float* pv1_b = (const float*)d_in[32];
  const float* pv2_w = (const float*)d_in[33];
  const float* pv2_b = (const float*)d_in[34];
  const int*   bev   = (const int*)d_in[35];

  float* out = (float*)d_out;
  float* out_fd  = out;
  float* out_h1  = out_fd + (size_t)16*(VOCABN+EXTRAN);
  float* out_c1  = out_h1 + 16*256;
  float* out_ct  = out_c1 + 16*256;
  float* out_a   = out_ct + 16*512;
  float* out_cov = out_a  + 16*460;

  float* ws = (float*)d_ws;
  size_t o = 0;
  float* sthat = ws + o; o += 16*512;
  float* wq    = ws + o; o += 16*8;
  float* cw    = ws + o; o += 16*32;
  float* WsS   = ws + o; o += 16*512;
  float* U4    = ws + o; o += (size_t)512*512;
  float* Wqr4  = ws + o; o += (size_t)512*512;
  float* q_t   = ws + o; o += (size_t)16*60*512;
  float* r_t   = ws + o; o += (size_t)16*400*512;
  float* qU    = ws + o; o += (size_t)16*60*512;
  float* aq    = ws + o; o += 16*4*64;
  float* ar    = ws + o; o += 16*4*112;
  float* e_b   = ws + o; o += 16*512;
  float* a_b   = ws + o; o += 16*512;
  float* hid_b = ws + o; o += 16*512;
  float* pgen  = ws + o; o += 64;
  float* Ssum  = ws + o; o += 64;
  float* logits= ws + o; o += (size_t)16*VOCABN;

  // zero accumulation targets (e_b, Ssum)
  hipMemsetAsync(e_b, 0, 16*512*sizeof(float), stream);
  hipMemsetAsync(Ssum, 0, 64*sizeof(float), stream);

  hipLaunchKernelGGL(k_w4, dim3(512), dim3(256), 0, stream, U_w, Wqr_w, U4, Wqr4);
  hipLaunchKernelGGL(k_head, dim3(16), dim3(1024), 0, stream,
      y_t,h0,c0,c_t_0,o_m,q_a,r_a,r_o,
      xc_w,xc_b,w_ih,w_hh,b_ih,b_hh,dsq_w,dsa_w,dso_w,Ws_w,
      sthat,out_h1,out_c1, wq,cw,WsS);
  hipLaunchKernelGGL(k_wsum, dim3(3680), dim3(256), 0, stream,
      h_q,h_r,wq,cw, q_t,r_t);
  hipLaunchKernelGGL(k_qU, dim3(480), dim3(256), 0, stream, q_t, U4, qU);
  hipLaunchKernelGGL(k_umax, dim3(64), dim3(1024), 0, stream, qU, r_t, aq, ar);
  hipLaunchKernelGGL(k_proj_e, dim3(928), dim3(256), 0, stream,
      q_t,r_t,aq,ar,q_mask,r_mask,Wqr4,Wqr_b,Wc_w,Vr_w,WsS,qr_cov, e_b);
  hipLaunchKernelGGL(k_attnfin, dim3(16), dim3(1024), 0, stream,
      e_b,q_mask,r_mask,qr_cov,q_t,r_t,aq,ar,sthat,pg_w,pg_b,pv1_w,pv1_b,
      a_b,hid_b,pgen, out_ct,out_a,out_cov);
  hipLaunchKernelGGL(k_logits, dim3((VOCABN+63)/64), dim3(256), 0, stream,
      hid_b, pv2_w, pv2_b, logits, Ssum);
  hipLaunchKernelGGL(k_scale, dim3((16*(VOCABN+EXTRAN)+255)/256), dim3(256), 0, stream,
      logits, extra_zeros, pgen, Ssum, out_fd);
  hipLaunchKernelGGL(k_scatter, dim3(16), dim3(512), 0, stream,
      a_b, pgen, bev, out_fd);
}

// Round 5
// 600.045 us; speedup vs baseline: 1.7955x; 1.1400x over previous
//
#include <hip/hip_runtime.h>
#include <math.h>

#define BB 16
#define VOCABN 50000
#define EXTRAN 100
#define LTOT 460
#define EPSF 1e-12f

__device__ __forceinline__ float sigm(float x){ return 1.0f/(1.0f+expf(-x)); }

__device__ __forceinline__ float wred(float v){
  #pragma unroll
  for (int s=32;s>0;s>>=1) v += __shfl_xor(v,s);
  return v;
}
__device__ __forceinline__ float wredmax(float v){
  #pragma unroll
  for (int s=32;s>0;s>>=1) v = fmaxf(v, __shfl_xor(v,s));
  return v;
}

// ======= K0: repack U_w, Wqr_w into [k4][col][4] layout ====================
__global__ __launch_bounds__(256) void k_w4(
    const float* __restrict__ A, const float* __restrict__ B,
    float* __restrict__ A4, float* __restrict__ B4)
{
  int idx = blockIdx.x*256 + threadIdx.x;
  int m = idx >> 16;
  int r = idx & 65535;
  int k4 = r >> 9;
  int h  = r & 511;
  const float* src = m ? B : A;
  float* dst = m ? B4 : A4;
  float4 v = *(const float4*)(src + (long)h*512 + k4*4);
  *(float4*)(dst + (long)k4*2048 + h*4) = v;
}

// ===== KA: xl = [y;c_t0] @ xc_w.T + b  (wave-per-row, 16 batches) ==========
__global__ __launch_bounds__(256) void k_xl(
    const float* __restrict__ y_t, const float* __restrict__ c_t_0,
    const float* __restrict__ xc_w, const float* __restrict__ xc_b,
    float* __restrict__ xls)
{
  __shared__ float cat[16*640];
  int t = threadIdx.x, w = t>>6, lane = t&63;
  for (int i=t;i<16*640;i+=256){
    int b2=i/640, d=i%640;
    cat[i] = (d<128)? y_t[b2*128+d] : c_t_0[b2*512 + d-128];
  }
  __syncthreads();
  int j = blockIdx.x*4 + w;
  const float* row = xc_w + (long)j*640;
  float acc[16]={};
  #pragma unroll
  for (int i=0;i<10;++i){
    float wv = row[lane+64*i];
    #pragma unroll
    for (int b2=0;b2<16;++b2) acc[b2] += wv*cat[b2*640 + lane+64*i];
  }
  float bias = xc_b[j];
  #pragma unroll
  for (int b2=0;b2<16;++b2){
    float v = wred(acc[b2]);
    if (lane==0) xls[b2*128+j] = v + bias;
  }
}

// ===== KB: gates = xl@w_ih.T + h0@w_hh.T + b  (wave-per-row, 16 b) =========
__global__ __launch_bounds__(256) void k_gates(
    const float* __restrict__ xls, const float* __restrict__ h0,
    const float* __restrict__ w_ih, const float* __restrict__ w_hh,
    const float* __restrict__ b_ih, const float* __restrict__ b_hh,
    float* __restrict__ gates)
{
  __shared__ float xh[16*384];
  int t = threadIdx.x, w = t>>6, lane = t&63;
  for (int i=t;i<16*384;i+=256){
    int b2=i/384, d=i%384;
    xh[i] = (d<128)? xls[b2*128+d] : h0[b2*256 + d-128];
  }
  __syncthreads();
  int r = blockIdx.x*4 + w;
  float acc[16]={};
  #pragma unroll
  for (int i=0;i<2;++i){
    float wv = w_ih[(long)r*128 + lane + 64*i];
    #pragma unroll
    for (int b2=0;b2<16;++b2) acc[b2] += wv*xh[b2*384 + lane+64*i];
  }
  #pragma unroll
  for (int i=0;i<4;++i){
    float wv = w_hh[(long)r*256 + lane + 64*i];
    #pragma unroll
    for (int b2=0;b2<16;++b2) acc[b2] += wv*xh[b2*384 + 128 + lane+64*i];
  }
  float bias = b_ih[r]+b_hh[r];
  #pragma unroll
  for (int b2=0;b2<16;++b2){
    float v = wred(acc[b2]);
    if (lane==0) gates[b2*1024 + r] = v + bias;
  }
}

// ===== KC: LSTM cell elementwise ==========================================
__global__ __launch_bounds__(256) void k_cell(
    const float* __restrict__ gates, const float* __restrict__ c0,
    float* __restrict__ sthat, float* __restrict__ out_h1, float* __restrict__ out_c1)
{
  int b = blockIdx.x, t = threadIdx.x;
  float gi = gates[b*1024+t], gf = gates[b*1024+256+t];
  float gg = gates[b*1024+512+t], go = gates[b*1024+768+t];
  float c1v = sigm(gf)*c0[b*256+t] + sigm(gi)*tanhf(gg);
  float h1v = sigm(go)*tanhf(c1v);
  sthat[b*512+t] = h1v; sthat[b*512+256+t] = c1v;
  out_h1[b*256+t] = h1v; out_c1[b*256+t] = c1v;
}

// ===== KD1: tmpq partial = s@dsq_w (split-K over 8 segs, atomic) ===========
__global__ __launch_bounds__(128) void k_tmpq(
    const float* __restrict__ sthat, const float* __restrict__ dsq_w,
    float* __restrict__ tmpq)
{
  __shared__ float sseg[64];
  int bid = blockIdx.x; int b = bid>>3, seg = bid&7;
  int d0 = seg*64, t = threadIdx.x;
  if (t<64) sseg[t] = sthat[b*512 + d0 + t];
  __syncthreads();
  float acc = 0.f;
  for (int d=0;d<64;++d) acc += sseg[d]*dsq_w[(long)(d0+d)*128 + t];
  atomicAdd(&tmpq[b*128+t], acc);
}

// ===== KD2: wq + qat =======================================================
__global__ __launch_bounds__(128) void k_wq(
    const float* __restrict__ tmpq, const float* __restrict__ q_a,
    float* __restrict__ wq_o, float* __restrict__ qat)
{
  __shared__ float tq[128], qa_l[640], wr2[5], wql[5], scal[1];
  int b = blockIdx.x, t = threadIdx.x;
  tq[t] = tmpq[b*128+t];
  for (int i=t;i<640;i+=128) qa_l[i] = q_a[b*640+i];
  __syncthreads();
  if (t<5){
    float p=0.f;
    for (int e2=0;e2<128;++e2) p += tq[e2]*qa_l[t*128+e2];
    wr2[t]=tanhf(p);
  }
  __syncthreads();
  if (t==0){ float sm=EPSF; for(int n=0;n<5;++n) sm+=wr2[n]; scal[0]=sm; }
  __syncthreads();
  if (t<5){ float v = wr2[t]/scal[0]; wql[t]=v; wq_o[b*5+t]=v; }
  __syncthreads();
  float a=0.f;
  #pragma unroll
  for (int n=0;n<5;++n) a += wql[n]*qa_l[n*128+t];
  qat[b*128+t]=a;
}

// ===== KD3: tmpa, tmpo (split-K atomic) + WsS (wave-per-row) ===============
__global__ __launch_bounds__(256) void k_mix(
    const float* __restrict__ sthat, const float* __restrict__ qat,
    const float* __restrict__ o_m,
    const float* __restrict__ dsa_w, const float* __restrict__ dso_w,
    const float* __restrict__ Ws_w,
    float* __restrict__ tmpa, float* __restrict__ tmpo, float* __restrict__ WsS)
{
  __shared__ float smem[8192];
  int bid = blockIdx.x, t = threadIdx.x;
  if (bid < 128){            // tmpa: K=640, 8 segs of 80
    int b = bid>>3, seg = bid&7, d0 = seg*80;
    if (t<80){
      int d = d0+t;
      smem[t] = (d<512)? sthat[b*512+d] : qat[b*128 + d-512];
    }
    __syncthreads();
    int j = t&127, half = t>>7;
    float acc=0.f;
    for (int dd=0;dd<40;++dd){
      int d = half*40+dd;
      acc += smem[d]*dsa_w[(long)(d0+d)*128 + j];
    }
    atomicAdd(&tmpa[b*128+j], acc);
  } else if (bid < 256){     // tmpo: K=1152, 8 segs of 144
    int idx = bid-128; int b = idx>>3, seg = idx&7, d0 = seg*144;
    for (int i=t;i<144;i+=256){
      int d = d0+i;
      smem[i] = (d<512)? sthat[b*512+d] : o_m[b*640 + d-512];
    }
    __syncthreads();
    int j = t&127, half = t>>7;
    float acc=0.f;
    for (int dd=0;dd<72;++dd){
      int d = half*72+dd;
      acc += smem[d]*dso_w[(long)(d0+d)*128 + j];
    }
    atomicAdd(&tmpo[b*128+j], acc);
  } else {                   // WsS: wave-per-h, 16 batches
    int idx = bid-256;       // 0..127
    int w = t>>6, lane = t&63;
    for (int i=t;i<8192;i+=256){
      smem[i] = sthat[i];    // s_all[16][512]
    }
    __syncthreads();
    int h = idx*4 + w;
    const float* row = Ws_w + (long)h*512;
    float acc[16]={};
    #pragma unroll
    for (int i=0;i<8;++i){
      float wv = row[lane+64*i];
      #pragma unroll
      for (int b2=0;b2<16;++b2) acc[b2] += wv*smem[b2*512 + lane+64*i];
    }
    #pragma unroll
    for (int b2=0;b2<16;++b2){
      float v = wred(acc[b2]);
      if (lane==0) WsS[b2*512+h] = v;
    }
  }
}

// ===== KD4: bilinear a/o weights + cw ======================================
__global__ __launch_bounds__(256) void k_cw(
    const float* __restrict__ tmpa, const float* __restrict__ tmpo,
    const float* __restrict__ r_a, const float* __restrict__ r_o,
    float* __restrict__ cw_o)
{
  __shared__ float ta[128], to[128], wra[20], wro[20], sa[4], so[4];
  int b = blockIdx.x, t = threadIdx.x, w = t>>6, lane = t&63;
  if (t<128) ta[t]=tmpa[b*128+t];
  else if (t<256) to[t-128]=tmpo[b*128+(t-128)];
  __syncthreads();
  for (int oo=w; oo<20; oo+=4){
    const float* ra = r_a + ((long)(b*20+oo))*128;
    const float* ro = r_o + ((long)(b*20+oo))*128;
    float pa = ta[lane]*ra[lane] + ta[lane+64]*ra[lane+64];
    float po = to[lane]*ro[lane] + to[lane+64]*ro[lane+64];
    pa = wred(pa); po = wred(po);
    if (lane==0){ wra[oo]=tanhf(pa); wro[oo]=tanhf(po); }
  }
  __syncthreads();
  if (t<4){
    float s1=EPSF, s2=EPSF;
    for (int n=0;n<5;++n){ s1+=wra[t*5+n]; s2+=wro[t*5+n]; }
    sa[t]=s1; so[t]=s2;
  }
  __syncthreads();
  if (t<20) cw_o[b*20+t] = wra[t]/sa[t/5] + wro[t]/so[t/5];
}

// =================== K2: q_t / r_t weighted sums ===========================
#define NQT4 (BB*60*128)
__global__ __launch_bounds__(256) void k_wsum(
    const float* __restrict__ h_q, const float* __restrict__ h_r,
    const float* __restrict__ wq, const float* __restrict__ cw,
    float* __restrict__ q_t, float* __restrict__ r_t)
{
  __shared__ float cf[5];
  long idx = (long)blockIdx.x*256 + threadIdx.x;
  if (blockIdx.x < 480) {
    int b = (int)(idx / (60*128));
    if (threadIdx.x < 5) cf[threadIdx.x] = wq[b*5+threadIdx.x];
    __syncthreads();
    int rem = (int)(idx % (60*128));
    int l = rem/128, h4 = rem&127;
    const float4* src = (const float4*)h_q;
    float4 acc = {0,0,0,0};
    #pragma unroll
    for (int n=0;n<5;++n){
      float4 v = src[(((long)(b*5+n)*60 + l)<<7) + h4];
      float ww = cf[n];
      acc.x += ww*v.x; acc.y += ww*v.y; acc.z += ww*v.z; acc.w += ww*v.w;
    }
    ((float4*)q_t)[((long)(b*60+l)<<7) + h4] = acc;
  } else {
    long j = idx - NQT4;
    int bk = (int)(j / (100*128));
    if (threadIdx.x < 5) cf[threadIdx.x] = cw[bk*5+threadIdx.x];
    __syncthreads();
    int rem = (int)(j % (100*128));
    int l = rem/128, h4 = rem&127;
    const float4* src = (const float4*)h_r;
    float4 acc = {0,0,0,0};
    #pragma unroll
    for (int n=0;n<5;++n){
      float4 v = src[(((long)(bk*5+n)*100 + l)<<7) + h4];
      float ww = cf[n];
      acc.x += ww*v.x; acc.y += ww*v.y; acc.z += ww*v.z; acc.w += ww*v.w;
    }
    ((float4*)r_t)[((long)(bk*100+l)<<7) + h4] = acc;
  }
}

// ======== K3: qU = q_t @ U^T — col-split, U4 layout ========================
__global__ __launch_bounds__(256) void k_qU(
    const float* __restrict__ q_t, const float* __restrict__ U4, float* __restrict__ qU)
{
  __shared__ float qt[4*512];
  int bid = blockIdx.x;
  int b = bid / 30; int r2 = bid % 30; int tile = r2 >> 1; int half = r2 & 1;
  int q0 = tile*4; int C0 = half*256;
  int t = threadIdx.x;
  {
    const float4* src = (const float4*)(q_t + (long)(b*60+q0)*512);
    ((float4*)qt)[t]     = src[t];
    ((float4*)qt)[t+256] = src[t+256];
  }
  __syncthreads();
  int c0 = t&63, rg = t>>6;
  float acc[4] = {};
  #pragma unroll 2
  for (int k4=0; k4<128; ++k4){
    float4 p = *(const float4*)&qt[rg*512 + k4*4];
    #pragma unroll
    for (int m=0;m<4;++m){
      float4 wv = *(const float4*)(U4 + (long)k4*2048 + (C0 + c0 + 64*m)*4);
      acc[m] += p.x*wv.x + p.y*wv.y + p.z*wv.z + p.w*wv.w;
    }
  }
  #pragma unroll
  for (int m=0;m<4;++m)
    qU[(long)(b*60+q0+rg)*512 + C0 + c0 + 64*m] = acc[m];
}

// ====== K4a: score GEMM + partial maxes (b,k,r-half tiles) =================
__global__ __launch_bounds__(256) void k_sc(
    const float* __restrict__ qU, const float* __restrict__ r_t,
    float* __restrict__ mqp, float* __restrict__ mrp)
{
  __shared__ float qs[64*65];
  __shared__ float rs[64*65];
  __shared__ float mqb[60*16];
  __shared__ float mrb[52*16];
  int bid = blockIdx.x;
  int b = bid>>3, k = (bid>>1)&3, half = bid&1;
  int t = threadIdx.x;
  const float* qbase = qU + (long)b*60*512;
  const float* rbase = r_t + ((long)(b*4+k)*100 + half*50)*512;
  int tq = t&15, tr = t>>4;
  int q0 = tq*4, r0 = tr*4;
  int nq = (q0<60)? ((60-q0<4)?(60-q0):4) : 0;
  int nr = (r0<50)? ((50-r0<4)?(50-r0):4) : 0;
  float acc[4][4]={};
  for (int c=0;c<8;++c){
    int k0 = c*64;
    for (int i=t;i<60*64;i+=256){ int q=i>>6, kk=i&63; qs[q*65+kk]=qbase[(long)q*512+k0+kk]; }
    for (int i=t;i<50*64;i+=256){ int r=i>>6, kk=i&63; rs[r*65+kk]=rbase[(long)r*512+k0+kk]; }
    __syncthreads();
    for (int kk=0;kk<64;++kk){
      float qv[4], rv[4];
      #pragma unroll
      for (int i=0;i<4;++i) qv[i]=qs[(q0+i)*65+kk];
      #pragma unroll
      for (int j=0;j<4;++j) rv[j]=rs[(r0+j)*65+kk];
      #pragma unroll
      for (int i=0;i<4;++i)
        #pragma unroll
        for (int j=0;j<4;++j) acc[i][j]+=qv[i]*rv[j];
    }
    __syncthreads();
  }
  if (nr>0){
    #pragma unroll
    for (int i=0;i<4;++i) if (i<nq){
      float m=-1e30f;
      #pragma unroll
      for (int j=0;j<4;++j) if (j<nr) m=fmaxf(m,acc[i][j]);
      mqb[(q0+i)*16+tr]=m;
    }
  }
  if (nq>0){
    #pragma unroll
    for (int j=0;j<4;++j) if (j<nr){
      float m=-1e30f;
      #pragma unroll
      for (int i=0;i<4;++i) if (i<nq) m=fmaxf(m,acc[i][j]);
      mrb[(r0+j)*16+tq]=m;
    }
  }
  __syncthreads();
  if (t<60){
    float m=-1e30f;
    for (int jj=0;jj<13;++jj) m=fmaxf(m,mqb[t*16+jj]);
    mqp[(long)bid*60 + t] = m;
  } else if (t>=64 && t<114){
    int rr=t-64;
    float m=-1e30f;
    for (int jj=0;jj<15;++jj) m=fmaxf(m,mrb[rr*16+jj]);
    mrp[((long)(b*4+k))*100 + half*50 + rr] = m;
  }
}

// ====== K4b: tanh + softmaxes over q (60) and r (100) ======================
__global__ __launch_bounds__(128) void k_alpha(
    const float* __restrict__ mqp, const float* __restrict__ mrp,
    float* __restrict__ aq, float* __restrict__ ar)
{
  __shared__ float uq[60], ur[100], scal[4];
  int bid = blockIdx.x, t = threadIdx.x;
  if (t<60){
    float m = fmaxf(mqp[(long)(bid*2)*60+t], mqp[(long)(bid*2+1)*60+t]);
    uq[t] = tanhf(m);
  }
  if (t<100) ur[t] = tanhf(mrp[(long)bid*100+t]);
  __syncthreads();
  if (t==0){
    float M=-1e30f; for (int q=0;q<60;++q) M=fmaxf(M,uq[q]);
    float S=0.f;    for (int q=0;q<60;++q) S+=expf(uq[q]-M);
    scal[0]=M; scal[2]=S;
  }
  if (t==64){
    float M=-1e30f; for (int r=0;r<100;++r) M=fmaxf(M,ur[r]);
    float S=0.f;    for (int r=0;r<100;++r) S+=expf(ur[r]-M);
    scal[1]=M; scal[3]=S;
  }
  __syncthreads();
  if (t<60)  aq[(long)bid*60+t]  = expf(uq[t]-scal[0])/scal[2];
  if (t<100) ar[(long)bid*100+t] = expf(ur[t]-scal[1])/scal[3];
}

// ====== K5: e += tanh(WsS + pai@Wqr^T + b + cov*Wc)·Vr (col-split) =========
__global__ __launch_bounds__(256) void k_proj_e(
    const float* __restrict__ q_t, const float* __restrict__ r_t,
    const float* __restrict__ aq, const float* __restrict__ ar,
    const float* __restrict__ q_mask, const float* __restrict__ r_mask,
    const float* __restrict__ W4, const float* __restrict__ Wqr_b,
    const float* __restrict__ Wc_w, const float* __restrict__ Vr_w,
    const float* __restrict__ WsS, const float* __restrict__ qr_cov,
    float* __restrict__ e_o)
{
  __shared__ float pt[16*512];
  __shared__ float cov[16], coef[16];
  int bid = blockIdx.x;
  int b = bid / 58; int r2 = bid % 58; int tile = r2 >> 1; int half = r2 & 1;
  int l0 = tile*16; int C0 = half*256;
  int t = threadIdx.x;
  int nrows = (460-l0 < 16)? (460-l0) : 16;
  if (t<16){
    float pc=0.f, cv=0.f;
    if (t<nrows){
      int l = l0+t;
      cv = qr_cov[b*460+l];
      if (l < 60){
        float s4 = aq[(b*4+0)*60+l]+aq[(b*4+1)*60+l]+aq[(b*4+2)*60+l]+aq[(b*4+3)*60+l];
        pc = s4 * q_mask[b*60+l] * 0.25f;
      } else {
        pc = ar[b*400+(l-60)] * r_mask[b*400+(l-60)];
      }
    }
    coef[t]=pc; cov[t]=cv;
  }
  __syncthreads();
  for (int i=t;i<2048;i+=256){
    int r = i>>7, d4 = i&127;
    float4 v = {0,0,0,0};
    if (r < nrows){
      int l = l0+r;
      v = (l<60) ? ((const float4*)q_t)[((long)(b*60+l)<<7)+d4]
                 : ((const float4*)r_t)[((long)(b*400+(l-60))<<7)+d4];
      float cf = coef[r];
      v.x*=cf; v.y*=cf; v.z*=cf; v.w*=cf;
    }
    ((float4*)pt)[i] = v;
  }
  __syncthreads();
  int c0 = t&63, rg = t>>6, r0 = rg*4;
  float acc[4][4] = {};
  #pragma unroll 2
  for (int k4=0; k4<128; ++k4){
    float4 wv[4];
    #pragma unroll
    for (int m=0;m<4;++m)
      wv[m] = *(const float4*)(W4 + (long)k4*2048 + (C0 + c0 + 64*m)*4);
    #pragma unroll
    for (int r=0;r<4;++r){
      float4 p = *(const float4*)&pt[(r0+r)*512 + k4*4];
      #pragma unroll
      for (int m=0;m<4;++m)
        acc[r][m] += p.x*wv[m].x + p.y*wv[m].y + p.z*wv[m].z + p.w*wv[m].w;
    }
  }
  float wsm[4], wbm[4], wcm[4], vrm[4];
  #pragma unroll
  for (int m=0;m<4;++m){
    int h = C0 + c0 + 64*m;
    wsm[m] = WsS[b*512+h]; wbm[m] = Wqr_b[h];
    wcm[m] = Wc_w[h];      vrm[m] = Vr_w[h];
  }
  int lane = t&63;
  #pragma unroll
  for (int r=0;r<4;++r){
    int row = r0+r;
    float cv = cov[row];
    float s = 0.f;
    #pragma unroll
    for (int m=0;m<4;++m)
      s += tanhf(wsm[m] + acc[r][m] + wbm[m] + cv*wcm[m]) * vrm[m];
    s = wred(s);
    if (lane==0 && row<nrows) atomicAdd(&e_o[b*460+l0+row], s);
  }
}

// ====== K6a: softmax over e + coef + outputs a/cov =========================
__global__ __launch_bounds__(512) void k_smax(
    const float* __restrict__ e_i, const float* __restrict__ q_mask,
    const float* __restrict__ r_mask, const float* __restrict__ qr_cov,
    const float* __restrict__ aq, const float* __restrict__ ar,
    float* __restrict__ a_o, float* __restrict__ coef_o,
    float* __restrict__ out_a, float* __restrict__ out_cov)
{
  __shared__ float red[8];
  int b = blockIdx.x, t = threadIdx.x, w = t>>6, lane = t&63;
  float ev = (t<460)? e_i[b*460+t] : -1e30f;
  float m = wredmax(ev);
  if (lane==0) red[w]=m;
  __syncthreads();
  float M=-1e30f;
  #pragma unroll
  for (int i=0;i<8;++i) M=fmaxf(M,red[i]);
  __syncthreads();
  float x = 0.f;
  if (t<460){
    float mk = (t<60) ? q_mask[b*60+t] : r_mask[b*400+(t-60)];
    x = expf(ev-M)*mk;
  }
  float sr = wred(x);
  if (lane==0) red[w]=sr;
  __syncthreads();
  float S=0.f;
  #pragma unroll
  for (int i=0;i<8;++i) S+=red[i];
  if (t<460){
    float v = x/S;
    a_o[b*460+t]=v; out_a[b*460+t]=v; out_cov[b*460+t]=qr_cov[b*460+t]+v;
    float pc;
    if (t<60){
      float s4 = aq[(b*4+0)*60+t]+aq[(b*4+1)*60+t]+aq[(b*4+2)*60+t]+aq[(b*4+3)*60+t];
      pc = s4 * q_mask[b*60+t] * 0.25f;
    } else {
      pc = ar[b*400+(t-60)] * r_mask[b*400+(t-60)];
    }
    coef_o[b*460+t]=v*pc;
  }
}

// ====== K6b: c_t = sum_l coef*pai  (l-split atomic) ========================
__global__ __launch_bounds__(256) void k_ct(
    const float* __restrict__ coef_o, const float* __restrict__ q_t,
    const float* __restrict__ r_t, float* __restrict__ ct)
{
  __shared__ float cf[58];
  int bid = blockIdx.x; int b = bid>>3, seg = bid&7;
  int l0 = seg*58; int ln = (460-l0<58)? (460-l0):58;
  int t = threadIdx.x;
  if (t<ln) cf[t]=coef_o[b*460+l0+t];
  __syncthreads();
  float a0=0.f, a1=0.f;
  for (int i=0;i<ln;++i){
    int l = l0+i;
    const float2* src = (l<60)? (const float2*)(q_t + ((long)(b*60+l)<<9))
                              : (const float2*)(r_t + ((long)(b*400+(l-60))<<9));
    float2 v = src[t];
    a0 += cf[i]*v.x; a1 += cf[i]*v.y;
  }
  atomicAdd(&ct[b*512 + 2*t],   a0);
  atomicAdd(&ct[b*512 + 2*t+1], a1);
}

// ====== K6c: pgen + out_ct =================================================
__global__ __launch_bounds__(256) void k_pgen(
    const float* __restrict__ sthat, const float* __restrict__ ct,
    const float* __restrict__ pg_w, const float* __restrict__ pg_b,
    float* __restrict__ pgen_o, float* __restrict__ out_ct)
{
  __shared__ float red[4];
  int b = blockIdx.x, t = threadIdx.x, lane = t&63, w = t>>6;
  float c1 = ct[b*512+t], c2 = ct[b*512+256+t];
  out_ct[b*512+t]=c1; out_ct[b*512+256+t]=c2;
  float p = sthat[b*512+t]*pg_w[t] + sthat[b*512+256+t]*pg_w[256+t]
          + c1*pg_w[512+t] + c2*pg_w[768+t];
  p = wred(p);
  if (lane==0) red[w]=p;
  __syncthreads();
  if (t==0) pgen_o[b]=sigm(red[0]+red[1]+red[2]+red[3]+pg_b[0]);
}

// ====== K6d: hid = [s;ct]@pv1^T + b  (wave-per-row, 16 b) ==================
__global__ __launch_bounds__(256) void k_hid(
    const float* __restrict__ sthat, const float* __restrict__ ct,
    const float* __restrict__ pv1_w, const float* __restrict__ pv1_b,
    float* __restrict__ hid)
{
  __shared__ float hst[16*1024];
  int t = threadIdx.x, w = t>>6, lane = t&63;
  for (int i=t;i<16*1024;i+=256){
    int b2=i>>10, d=i&1023;
    hst[i] = (d<512)? sthat[b2*512+d] : ct[b2*512 + d-512];
  }
  __syncthreads();
  int h = blockIdx.x*4 + w;
  const float* row = pv1_w + (long)h*1024;
  float acc[16]={};
  #pragma unroll
  for (int i=0;i<16;++i){
    float wv = row[lane+64*i];
    #pragma unroll
    for (int b2=0;b2<16;++b2) acc[b2] += wv*hst[b2*1024 + lane+64*i];
  }
  float bias = pv1_b[h];
  #pragma unroll
  for (int b2=0;b2<16;++b2){
    float v = wred(acc[b2]);
    if (lane==0) hid[b2*512+h] = v + bias;
  }
}

// ====== K7: vocab exp-logits + per-batch expsum partials ===================
__global__ __launch_bounds__(256) void k_logits(
    const float* __restrict__ hid, const float* __restrict__ pv2_w, const float* __restrict__ pv2_b,
    float* __restrict__ logits, float* __restrict__ S)
{
  __shared__ float hs[16*512];
  __shared__ float ssum[16];
  int t = threadIdx.x;
  for (int i=t;i<8192;i+=256) hs[i]=hid[i];
  if (t<16) ssum[t]=0.f;
  __syncthreads();
  int vl = t>>2, seg = t&3;
  long v = (long)blockIdx.x*64 + vl;
  float acc[16]={};
  if (v < VOCABN){
    const float4* wr = (const float4*)(pv2_w + v*512 + seg*128);
    const float4* hv = ((const float4*)hs) + seg*32;
    for (int i=0;i<32;++i){
      int j = (i + seg*2)&31;
      float4 wv = wr[j];
      #pragma unroll
      for (int b2=0;b2<16;++b2){
        float4 h = hv[b2*128+j];
        acc[b2] += wv.x*h.x+wv.y*h.y+wv.z*h.z+wv.w*h.w;
      }
    }
  }
  #pragma unroll
  for (int b2=0;b2<16;++b2){
    acc[b2] += __shfl_xor(acc[b2],1);
    acc[b2] += __shfl_xor(acc[b2],2);
  }
  float bias = (v < VOCABN) ? pv2_b[v] : 0.f;
  int lane = t&63;
  #pragma unroll
  for (int b2=0;b2<16;++b2){
    float el = (v < VOCABN) ? expf(acc[b2]+bias) : 0.f;
    if (seg==0 && v < VOCABN) logits[(long)b2*VOCABN+v] = el;
    float c = (seg==0) ? el : 0.f;
    c = wred(c);
    if (lane==0) atomicAdd(&ssum[b2], c);
  }
  __syncthreads();
  if (t<16) atomicAdd(&S[t], ssum[t]);
}

// ====== K8: scale pass =====================================================
__global__ __launch_bounds__(256) void k_scale(
    const float* __restrict__ logits, const float* __restrict__ extra_zeros,
    const float* __restrict__ pgen, const float* __restrict__ S,
    float* __restrict__ out)
{
  long idx = (long)blockIdx.x*256 + threadIdx.x;
  if (idx >= (long)BB*(VOCABN+EXTRAN)) return;
  int b = (int)(idx / (VOCABN+EXTRAN));
  int j = (int)(idx % (VOCABN+EXTRAN));
  if (j < VOCABN){
    out[idx] = logits[(long)b*VOCABN+j] * (pgen[b]/S[b]);
  } else {
    out[idx] = extra_zeros[b*EXTRAN + (j-VOCABN)];
  }
}

// ====== K9: scatter-add ====================================================
__global__ __launch_bounds__(512) void k_scatter(
    const float* __restrict__ a_ws, const float* __restrict__ pgen,
    const int* __restrict__ bev, float* __restrict__ out)
{
  int b = blockIdx.x, t = threadIdx.x;
  if (t < LTOT){
    float opg = 1.0f - pgen[b];
    atomicAdd(&out[(long)b*(VOCABN+EXTRAN) + bev[b*460+t]], opg*a_ws[b*460+t]);
  }
}

extern "C" void kernel_launch(void* const* d_in, const int* in_sizes, int n_in,
                              void* d_out, int out_size, void* d_ws, size_t ws_size,
                              hipStream_t stream)
{
  (void)in_sizes; (void)n_in; (void)out_size; (void)ws_size;
  const float* y_t   = (const float*)d_in[0];
  const float* h0    = (const float*)d_in[1];
  const float* c0    = (const float*)d_in[2];
  const float* c_t_0 = (const float*)d_in[3];
  const float* o_m   = (const float*)d_in[4];
  const float* h_q   = (const float*)d_in[5];
  const float* q_mask= (const float*)d_in[6];
  const float* q_a   = (const float*)d_in[7];
  const float* h_r   = (const float*)d_in[8];
  const float* r_mask= (const float*)d_in[9];
  const float* r_a   = (const float*)d_in[10];
  const float* r_o   = (const float*)d_in[11];
  const float* qr_cov= (const float*)d_in[12];
  const float* extra_zeros=(const float*)d_in[13];
  const float* xc_w  = (const float*)d_in[14];
  const float* xc_b  = (const float*)d_in[15];
  const float* w_ih  = (const float*)d_in[16];
  const float* w_hh  = (const float*)d_in[17];
  const float* b_ih  = (const float*)d_in[18];
  const float* b_hh  = (const float*)d_in[19];
  const float* dsq_w = (const float*)d_in[20];
  const float* dsa_w = (const float*)d_in[21];
  const float* dso_w = (const float*)d_in[22];
  const float* U_w   = (const float*)d_in[23];
  const float* Wc_w  = (const float*)d_in[24];
  const float* Ws_w  = (const float*)d_in[25];
  const float* Wqr_w = (const float*)d_in[26];
  const float* Wqr_b = (const float*)d_in[27];
  const float* Vr_w  = (const float*)d_in[28];
  const float* pg_w  = (const float*)d_in[29];
  const float* pg_b  = (const float*)d_in[30];
  const float* pv1_w = (const float*)d_in[31];
  const float* pv1_b = (const float*)d_in[32];
  const float* pv2_w = (const float*)d_in[33];
  const float* pv2_b = (const float*)d_in[34];
  const int*   bev   = (const int*)d_in[35];

  float* out = (float*)d_out;
  float* out_fd  = out;
  float* out_h1  = out_fd + (size_t)16*(VOCABN+EXTRAN);
  float* out_c1  = out_h1 + 16*256;
  float* out_ct  = out_c1 + 16*256;
  float* out_a   = out_ct + 16*512;
  float* out_cov = out_a  + 16*460;

  float* ws = (float*)d_ws;
  size_t o = 0;
  // ---- zero region (single memset) ----
  float* zbase = ws + o;
  float* tmpq  = ws + o; o += 2048;
  float* tmpa  = ws + o; o += 2048;
  float* tmpo  = ws + o; o += 2048;
  float* e_b   = ws + o; o += 7360;
  float* ct    = ws + o; o += 8192;
  float* Ssum  = ws + o; o += 64;
  size_t zcount = o;
  // ---- rest ----
  float* sthat = ws + o; o += 8192;
  float* xls   = ws + o; o += 2048;
  float* gates = ws + o; o += 16384;
  float* wq    = ws + o; o += 128;
  float* qat   = ws + o; o += 2048;
  float* cw    = ws + o; o += 512;
  float* WsS   = ws + o; o += 8192;
  float* U4    = ws + o; o += (size_t)512*512;
  float* Wqr4  = ws + o; o += (size_t)512*512;
  float* q_t   = ws + o; o += (size_t)16*60*512;
  float* r_t   = ws + o; o += (size_t)16*400*512;
  float* qU    = ws + o; o += (size_t)16*60*512;
  float* aq    = ws + o; o += 3840;
  float* ar    = ws + o; o += 6400;
  float* mqp   = ws + o; o += 7680;
  float* mrp   = ws + o; o += 6400;
  float* coefb = ws + o; o += 7360;
  float* a_b   = ws + o; o += 7360;
  float* hid_b = ws + o; o += 8192;
  float* pgen  = ws + o; o += 64;
  float* logits= ws + o; o += (size_t)16*VOCABN;

  hipMemsetAsync(zbase, 0, zcount*sizeof(float), stream);
  hipLaunchKernelGGL(k_w4, dim3(512), dim3(256), 0, stream, U_w, Wqr_w, U4, Wqr4);
  hipLaunchKernelGGL(k_xl, dim3(32), dim3(256), 0, stream, y_t, c_t_0, xc_w, xc_b, xls);
  hipLaunchKernelGGL(k_gates, dim3(256), dim3(256), 0, stream,
      xls, h0, w_ih, w_hh, b_ih, b_hh, gates);
  hipLaunchKernelGGL(k_cell, dim3(16), dim3(256), 0, stream,
      gates, c0, sthat, out_h1, out_c1);
  hipLaunchKernelGGL(k_tmpq, dim3(128), dim3(128), 0, stream, sthat, dsq_w, tmpq);
  hipLaunchKernelGGL(k_wq, dim3(16), dim3(128), 0, stream, tmpq, q_a, wq, qat);
  hipLaunchKernelGGL(k_mix, dim3(384), dim3(256), 0, stream,
      sthat, qat, o_m, dsa_w, dso_w, Ws_w, tmpa, tmpo, WsS);
  hipLaunchKernelGGL(k_cw, dim3(16), dim3(256), 0, stream, tmpa, tmpo, r_a, r_o, cw);
  hipLaunchKernelGGL(k_wsum, dim3(3680), dim3(256), 0, stream,
      h_q, h_r, wq, cw, q_t, r_t);
  hipLaunchKernelGGL(k_qU, dim3(480), dim3(256), 0, stream, q_t, U4, qU);
  hipLaunchKernelGGL(k_sc, dim3(128), dim3(256), 0, stream, qU, r_t, mqp, mrp);
  hipLaunchKernelGGL(k_alpha, dim3(64), dim3(128), 0, stream, mqp, mrp, aq, ar);
  hipLaunchKernelGGL(k_proj_e, dim3(928), dim3(256), 0, stream,
      q_t, r_t, aq, ar, q_mask, r_mask, Wqr4, Wqr_b, Wc_w, Vr_w, WsS, qr_cov, e_b);
  hipLaunchKernelGGL(k_smax, dim3(16), dim3(512), 0, stream,
      e_b, q_mask, r_mask, qr_cov, aq, ar, a_b, coefb, out_a, out_cov);
  hipLaunchKernelGGL(k_ct, dim3(128), dim3(256), 0, stream, coefb, q_t, r_t, ct);
  hipLaunchKernelGGL(k_pgen, dim3(16), dim3(256), 0, stream,
      sthat, ct, pg_w, pg_b, pgen, out_ct);
  hipLaunchKernelGGL(k_hid, dim3(128), dim3(256), 0, stream,
      sthat, ct, pv1_w, pv1_b, hid_b);
  hipLaunchKernelGGL(k_logits, dim3((VOCABN+63)/64), dim3(256), 0, stream,
      hid_b, pv2_w, pv2_b, logits, Ssum);
  hipLaunchKernelGGL(k_scale, dim3((16*(VOCABN+EXTRAN)+255)/256), dim3(256), 0, stream,
      logits, extra_zeros, pgen, Ssum, out_fd);
  hipLaunchKernelGGL(k_scatter, dim3(16), dim3(512), 0, stream,
      a_b, pgen, bev, out_fd);
}